// Round 14
// baseline (165.489 us; speedup 1.0000x reference)
//
#include <hip/hip_runtime.h>

// MHA: B=2, S=2048, D=1024, H=16, HD=64, causal, scale=1/8.
// Round 14: attn6 — barrier-free wave-private KV streams. Each wave owns one
// 32-row q-tile + private dbuf K/V LDS (16KB/wave); sync is per-wave
// s_waitcnt vmcnt(0)+sched_barrier only (no __syncthreads, no merges).
// KVBLK=32. Task map: rank r -> tile 63-(r&63), bh r>>6 (equal-length waves
// per block, heavy-first dispatch, 4 heads per XCD L2). Math blocks are the
// attn4-verified code specialized to one 32x32 tile. gemm256 / gemm128o /
// cvt_x / cvt_wt / trV unchanged from round 13.
//   ws layout (bytes):
//     [0,8M)    Xbf  : x as bf16 [4096,1024]
//     [8M,16M)  WT   : WqT,WkT,WvT,WoT bf16 [1024,1024] each ([N][K])
//     [16M,32M) Q,K  : [B,H,S,HD] bf16
//     [32M,40M) Vt   : [B,H,HD,S] bf16 (written by trV)
//     [40M,48M) CTX  : first V row-major (gemm256 out), then ctx [B,S,D]

#define S_LEN 2048
#define DMODEL 1024
#define NHEAD 16
#define HDIM 64
#define MROWS 4096  // B*S

typedef __bf16 bf16x8 __attribute__((ext_vector_type(8)));
typedef float f32x4 __attribute__((ext_vector_type(4)));
typedef float f32x16 __attribute__((ext_vector_type(16)));

__device__ __forceinline__ ushort f2bf(float f) {
  union { float f; unsigned u; } v; v.f = f;
  unsigned r = v.u + 0x7fffu + ((v.u >> 16) & 1u);  // RNE
  return (ushort)(r >> 16);
}

__device__ __forceinline__ void gload_lds16(const ushort* g, ushort* l) {
  __builtin_amdgcn_global_load_lds(
      (const __attribute__((address_space(1))) void*)g,
      (__attribute__((address_space(3))) void*)l, 16, 0, 0);
}

// pack two f32 -> one dword of 2 bf16 (compiler emits v_cvt_pk_bf16_f32)
__device__ __forceinline__ unsigned pack2bf(float lo, float hi) {
  union { __bf16 h[2]; unsigned u; } t;
  t.h[0] = (__bf16)lo; t.h[1] = (__bf16)hi;
  return t.u;
}

#if __has_builtin(__builtin_amdgcn_permlane32_swap)
#define HAVE_PL32 1
// after call: a = {a.lo | b.lo}, b = {a.hi | b.hi}  (lane<32 | lane>=32)
__device__ __forceinline__ void pl32sw(unsigned& a, unsigned& b) {
  auto r = __builtin_amdgcn_permlane32_swap((int)a, (int)b, false, false);
  a = (unsigned)r[0];
  b = (unsigned)r[1];
}
#endif

__device__ __forceinline__ float halfcomb_max(float x) {
#ifdef HAVE_PL32
  unsigned a = __float_as_uint(x), b = a;
  pl32sw(a, b);
  return fmaxf(__uint_as_float(a), __uint_as_float(b));
#else
  return fmaxf(x, __shfl_xor(x, 32, 64));
#endif
}
__device__ __forceinline__ float halfcomb_sum(float x) {
#ifdef HAVE_PL32
  unsigned a = __float_as_uint(x), b = a;
  pl32sw(a, b);
  return __uint_as_float(a) + __uint_as_float(b);
#else
  return x + __shfl_xor(x, 32, 64);
#endif
}

// per-wave vmem drain + scheduling fence (rule #18)
#define VMWAIT0                                      \
  do {                                               \
    asm volatile("s_waitcnt vmcnt(0)" ::: "memory"); \
    __builtin_amdgcn_sched_barrier(0);               \
  } while (0)

// ---------------- conversion kernels ----------------

__global__ __launch_bounds__(256) void cvt_x(const float* __restrict__ x,
                                             ushort* __restrict__ xb) {
  int i = (blockIdx.x * 256 + threadIdx.x) * 4;
  float4 v = *(const float4*)&x[i];
  ushort4 o;
  o.x = f2bf(v.x); o.y = f2bf(v.y); o.z = f2bf(v.z); o.w = f2bf(v.w);
  *(ushort4*)&xb[i] = o;
}

// W [K][N] fp32 -> WT [N][K] bf16, 64x64 tiles, vectorized
__global__ __launch_bounds__(256) void cvt_wt(const float* __restrict__ W0,
                                              const float* __restrict__ W1,
                                              const float* __restrict__ W2,
                                              const float* __restrict__ W3,
                                              ushort* __restrict__ out) {
  const float* W = blockIdx.z == 0 ? W0 : blockIdx.z == 1 ? W1
                   : blockIdx.z == 2 ? W2 : W3;
  ushort* WT = out + (size_t)blockIdx.z * DMODEL * DMODEL;
  __shared__ float tile[64][65];
  const int n0 = blockIdx.x * 64, k0 = blockIdx.y * 64;
#pragma unroll
  for (int i = 0; i < 4; ++i) {
    int chunk = i * 256 + threadIdx.x;  // 0..1023
    int r = chunk >> 4, c4 = chunk & 15;
    float4 v = *(const float4*)&W[(size_t)(k0 + r) * DMODEL + n0 + c4 * 4];
    tile[r][c4 * 4 + 0] = v.x; tile[r][c4 * 4 + 1] = v.y;
    tile[r][c4 * 4 + 2] = v.z; tile[r][c4 * 4 + 3] = v.w;
  }
  __syncthreads();
#pragma unroll
  for (int i = 0; i < 4; ++i) {
    int chunk = i * 256 + threadIdx.x;
    int r = chunk >> 4, c4 = chunk & 15;
    ushort4 o;
    o.x = f2bf(tile[c4 * 4 + 0][r]); o.y = f2bf(tile[c4 * 4 + 1][r]);
    o.z = f2bf(tile[c4 * 4 + 2][r]); o.w = f2bf(tile[c4 * 4 + 3][r]);
    *(ushort4*)&WT[(size_t)(n0 + r) * DMODEL + k0 + c4 * 4] = o;
  }
}

// V [B,H,S,HD] -> Vt [B,H,HD,S], 32x32 LDS tiles
__global__ __launch_bounds__(256) void trV(const ushort* __restrict__ V,
                                           ushort* __restrict__ Vt) {
  const int bh = blockIdx.z;
  const ushort* src = V + (size_t)bh * S_LEN * HDIM;
  ushort* dst = Vt + (size_t)bh * HDIM * S_LEN;
  __shared__ ushort tile[32][33];
  int s0 = blockIdx.x * 32, h0 = blockIdx.y * 32;
  int tx = threadIdx.x & 31, ty = threadIdx.x >> 5;  // 32 x 8
#pragma unroll
  for (int i = 0; i < 32; i += 8)
    tile[ty + i][tx] = src[(size_t)(s0 + ty + i) * HDIM + h0 + tx];
  __syncthreads();
#pragma unroll
  for (int i = 0; i < 32; i += 8)
    dst[(size_t)(h0 + ty + i) * S_LEN + s0 + tx] = tile[tx][ty + i];
}

// ---------------- QKV GEMM: 256x192 tile, 8 waves, phase-paced ------------
__global__ __launch_bounds__(512) void gemm256(
    const ushort* __restrict__ A, const ushort* __restrict__ Bt,
    const float* __restrict__ b0, const float* __restrict__ b1,
    const float* __restrict__ b2, ushort* __restrict__ outQ,
    ushort* __restrict__ outK, ushort* __restrict__ outV) {
  const int flat = blockIdx.y * 16 + blockIdx.x;       // 0..255
  const int swz = (flat & 7) * 32 + (flat >> 3);       // bijective (256=8*32)
  const int bx = swz & 15, by = swz >> 4;
  const int m0 = bx * 256, n0 = by * 192;

  __shared__ __align__(16) ushort Al[2][256 * 64];  // 64 KB
  __shared__ __align__(16) ushort Bl[2][192 * 64];  // 48 KB

  const int tid = threadIdx.x;
  const int lane = tid & 63, wid = tid >> 6;
  const int wr = wid >> 2, wc = wid & 3;
  const int fr = lane & 15, hi16 = lane >> 4;

  f32x4 acc[8][3] = {};

#pragma unroll
  for (int l = 0; l < 4; ++l) {
    int chunk = l * 512 + tid;
    int row = chunk >> 3, cpos = chunk & 7;
    int scol = (cpos ^ (row & 7)) * 8;
    gload_lds16(&A[(size_t)(m0 + row) * DMODEL + scol], &Al[0][chunk * 8]);
  }
#pragma unroll
  for (int l = 0; l < 3; ++l) {
    int chunk = l * 512 + tid;
    int row = chunk >> 3, cpos = chunk & 7;
    int scol = (cpos ^ (row & 7)) * 8;
    gload_lds16(&Bt[(size_t)(n0 + row) * DMODEL + scol], &Bl[0][chunk * 8]);
  }
  __syncthreads();

  for (int t = 0; t < 16; ++t) {
    const int bt = t & 1;
    bf16x8 bfr[3];
#pragma unroll
    for (int s = 0; s < 4; ++s) {
      const int kk = s >> 1, mh = s & 1;
      bf16x8 af[4];
#pragma unroll
      for (int q = 0; q < 4; ++q) {
        int rl = wr * 128 + (mh * 4 + q) * 16 + fr;
        af[q] = *(const bf16x8*)&Al[bt][rl * 64 +
                                        ((kk * 4 + hi16) ^ (rl & 7)) * 8];
      }
      if (mh == 0) {
#pragma unroll
        for (int nf = 0; nf < 3; ++nf) {
          int rl = wc * 48 + nf * 16 + fr;
          bfr[nf] = *(const bf16x8*)&Bl[bt][rl * 64 +
                                            ((kk * 4 + hi16) ^ (rl & 7)) * 8];
        }
      }
      if (t + 1 < 16 && s < 2) {
        const int k64 = (t + 1) * 64;
        if (s == 0) {
#pragma unroll
          for (int l = 0; l < 4; ++l) {
            int chunk = l * 512 + tid;
            int row = chunk >> 3, cpos = chunk & 7;
            int scol = (cpos ^ (row & 7)) * 8;
            gload_lds16(&A[(size_t)(m0 + row) * DMODEL + k64 + scol],
                        &Al[bt ^ 1][chunk * 8]);
          }
        } else {
#pragma unroll
          for (int l = 0; l < 3; ++l) {
            int chunk = l * 512 + tid;
            int row = chunk >> 3, cpos = chunk & 7;
            int scol = (cpos ^ (row & 7)) * 8;
            gload_lds16(&Bt[(size_t)(n0 + row) * DMODEL + k64 + scol],
                        &Bl[bt ^ 1][chunk * 8]);
          }
        }
      }
      __builtin_amdgcn_s_barrier();
      __builtin_amdgcn_s_setprio(1);
#pragma unroll
      for (int q = 0; q < 4; ++q)
#pragma unroll
        for (int nf = 0; nf < 3; ++nf)
          acc[mh * 4 + q][nf] = __builtin_amdgcn_mfma_f32_16x16x32_bf16(
              af[q], bfr[nf], acc[mh * 4 + q][nf], 0, 0, 0);
      __builtin_amdgcn_s_setprio(0);
      if (s < 3) __builtin_amdgcn_s_barrier();
    }
    __syncthreads();
  }

#pragma unroll
  for (int mf = 0; mf < 8; ++mf) {
#pragma unroll
    for (int nf = 0; nf < 3; ++nf) {
      int col = n0 + wc * 48 + nf * 16 + fr;
      int z = col >> 10, cw = col & 1023;
      float bval = z == 0 ? b0[cw] : z == 1 ? b1[cw] : b2[cw];
      int h = cw >> 6, hd = cw & (HDIM - 1);
      ushort* dst = (z == 0) ? outQ : (z == 1) ? outK : outV;
#pragma unroll
      for (int rg = 0; rg < 4; ++rg) {
        int row = m0 + wr * 128 + mf * 16 + hi16 * 4 + rg;
        int b = row >> 11, sq = row & (S_LEN - 1);
        float val = acc[mf][nf][rg] + bval;
        dst[(((size_t)(b * NHEAD + h)) * S_LEN + sq) * HDIM + hd] = f2bf(val);
      }
    }
  }
}

// ---------------- out-proj GEMM (128x128 tile, BK=64, 2-phase dbuf) -------
__global__ __launch_bounds__(256) void gemm128o(
    const ushort* __restrict__ A, const ushort* __restrict__ Bt,
    const float* __restrict__ b0, float* __restrict__ outB) {
  const int NT = 256;
  const int flat = blockIdx.y * 32 + blockIdx.x;
  const int swz = (flat & 7) * (NT >> 3) + (flat >> 3);
  const int bx = swz & 31, by = swz >> 5;
  const int m0 = bx * 128, n0 = by * 128;

  __shared__ __align__(16) ushort Alds[2][128 * 64];
  __shared__ __align__(16) ushort Blds[2][128 * 64];

  const int tid = threadIdx.x;
  const int lane = tid & 63, w = tid >> 6;
  const int wr = w >> 1, wc = w & 1;
  const int fr = lane & 15, hi16 = lane >> 4;

  f32x4 acc[4][4] = {};

  auto STAGE = [&](int kt, int bi) {
#pragma unroll
    for (int it = 0; it < 4; ++it) {
      int c = it * 256 + tid;
      int row = c >> 3;
      int sc = ((c & 7) ^ (row & 7)) * 8;
      int ldsbase = (it * 256 + w * 64) * 8;
      gload_lds16(&A[(size_t)(m0 + row) * DMODEL + kt + sc],
                  &Alds[bi][ldsbase]);
      gload_lds16(&Bt[(size_t)(n0 + row) * DMODEL + kt + sc],
                  &Blds[bi][ldsbase]);
    }
  };

  auto COMPUTE = [&](int bi) {
#pragma unroll
    for (int kk = 0; kk < 2; ++kk) {
      bf16x8 af[4], bfr[4];
#pragma unroll
      for (int i = 0; i < 4; ++i) {
        int row = wr * 64 + i * 16 + fr;
        af[i] = *(const bf16x8*)&Alds[bi][row * 64 +
                                          ((kk * 4 + hi16) ^ (row & 7)) * 8];
      }
#pragma unroll
      for (int j = 0; j < 4; ++j) {
        int row = wc * 64 + j * 16 + fr;
        bfr[j] = *(const bf16x8*)&Blds[bi][row * 64 +
                                           ((kk * 4 + hi16) ^ (row & 7)) * 8];
      }
#pragma unroll
      for (int i = 0; i < 4; ++i)
#pragma unroll
        for (int j = 0; j < 4; ++j)
          acc[i][j] = __builtin_amdgcn_mfma_f32_16x16x32_bf16(af[i], bfr[j],
                                                              acc[i][j], 0, 0, 0);
    }
  };

  STAGE(0, 0);
  __syncthreads();
  int buf = 0;
  for (int kt = 64; kt < DMODEL; kt += 64) {
    STAGE(kt, buf ^ 1);
    COMPUTE(buf);
    __syncthreads();
    buf ^= 1;
  }
  COMPUTE(buf);

#pragma unroll
  for (int i = 0; i < 4; ++i) {
#pragma unroll
    for (int j = 0; j < 4; ++j) {
      int col = n0 + wc * 64 + j * 16 + fr;
      float bval = b0[col];
#pragma unroll
      for (int r = 0; r < 4; ++r) {
        int row = m0 + wr * 64 + i * 16 + hi16 * 4 + r;
        outB[(size_t)row * DMODEL + col] = acc[i][j][r] + bval;
      }
    }
  }
}

// ---------------- flash attention (causal), wave-private streams ----------
// 512 blocks x 4 waves. Wave task rank r = work*4+wid: bh = r>>6,
// q-tile jt = 63-(r&63) (32 rows). Private dbuf K/V LDS per wave; per-wave
// vmcnt sync only — NO block barriers, NO merges. KVBLK=32.
__global__ __launch_bounds__(256, 2) void attn6(const ushort* __restrict__ Q,
                                                const ushort* __restrict__ K,
                                                const ushort* __restrict__ Vt,
                                                ushort* __restrict__ ctx) {
  const int blk = blockIdx.x;
  const int w = (blk & 7) * 64 + (blk >> 3);  // chunked XCD work id
  const int lane = threadIdx.x & 63, wid = threadIdx.x >> 6;
  const int r = w * 4 + wid;                  // 0..2047
  const int bh = r >> 6;                      // 4 heads per XCD chunk
  const int jt = 63 - (r & 63);               // 32-row q-tile, heavy first
  const int b = bh >> 4, h = bh & 15;
  const int q32 = lane & 31, hi = lane >> 5;
  const bool lo_half = (hi == 0);
  const int qrow = jt * 32 + q32;
  const int sw = (q32 & 7);                   // read-side swizzle

  const ushort* Qb = Q + (size_t)bh * S_LEN * HDIM;
  const ushort* Kb = K + (size_t)bh * S_LEN * HDIM;
  const ushort* Vb = Vt + (size_t)bh * HDIM * S_LEN;

  // per-wave private tiles: [wave][buf][32 rows x 64 bf16] = 4 KB each
  __shared__ __align__(16) ushort Kl[4][2][32 * 64];  // 32 KB
  __shared__ __align__(16) ushort Vl[4][2][32 * 64];  // 32 KB

  const float C = 0.125f * 1.44269504f;  // scale * log2(e)

  bf16x8 qf[4];
#pragma unroll
  for (int s = 0; s < 4; ++s)
    qf[s] = *(const bf16x8*)&Qb[(size_t)qrow * HDIM + s * 16 + hi * 8];

  f32x16 oacc[2] = {};
  float mraw = -1e30f, lsum = 0.f;

  // stage KV step s into buf bi (K: [kv][hd]; V: packed [r][t2*32+kc*8])
  auto STG = [&](int s, int bi) {
    const int kv0 = s * 32;
#pragma unroll
    for (int g = 0; g < 4; ++g) {
      int c = g * 64 + lane;              // K chunk 0..255
      int row = c >> 3, cp = c & 7;
      int sc = (cp ^ (row & 7)) * 8;      // inverse-swizzled source col
      gload_lds16(&Kb[(size_t)(kv0 + row) * HDIM + sc],
                  &Kl[wid][bi][c * 8]);
    }
#pragma unroll
    for (int g = 0; g < 4; ++g) {
      int c = g * 64 + lane;              // V chunk 0..255
      int row = c >> 3, cp = c & 7;
      int sc2 = cp ^ (row & 7);
      int t2 = sc2 >> 2, kc = sc2 & 3;
      gload_lds16(&Vb[(size_t)(t2 * 32 + row) * S_LEN + kv0 + kc * 8],
                  &Vl[wid][bi][c * 8]);
    }
  };

  STG(0, 0);
  VMWAIT0;
  int buf = 0;

  for (int s = 0; s <= jt; ++s) {
    if (s < jt) STG(s + 1, buf ^ 1);  // issue-early; hides under compute
    const int kv0 = s * 32;

    // ---- QK^T: S^T[k][q], one 32x32 tile ----
    f32x16 sa = {};
    __builtin_amdgcn_s_setprio(1);
#pragma unroll
    for (int sl = 0; sl < 4; ++sl) {
      bf16x8 kf = *(const bf16x8*)&Kl[wid][buf][q32 * 64 +
                                                ((sl * 2 + hi) ^ sw) * 8];
      sa = __builtin_amdgcn_mfma_f32_32x32x16_bf16(kf, qf[sl], sa, 0, 0, 0);
    }
    __builtin_amdgcn_s_setprio(0);

    // ---- V^T A-frags: vf[t2][s16] covers hd t2*32+q32, kv s16*16+hi*8 ----
    bf16x8 vf[2][2];
#pragma unroll
    for (int t2 = 0; t2 < 2; ++t2)
#pragma unroll
      for (int s16 = 0; s16 < 2; ++s16)
        vf[t2][s16] = *(const bf16x8*)&Vl[wid][buf][
            q32 * 64 + ((t2 * 4 + s16 * 2 + hi) ^ sw) * 8];

    // ---- causal mask (final step only; wave-uniform branch) ----
    if (s == jt) {
      const int khi = kv0 + 4 * hi;
#pragma unroll
      for (int rr = 0; rr < 16; ++rr) {
        int kg = khi + (rr & 3) + 8 * (rr >> 2);
        if (kg > qrow) sa[rr] = -1e30f;
      }
    }

    // ---- online softmax (raw domain; lane-local rows) ----
    float tmv[8];
#pragma unroll
    for (int rr = 0; rr < 8; ++rr) tmv[rr] = fmaxf(sa[rr], sa[rr + 8]);
    float t0 = fmaxf(fmaxf(tmv[0], tmv[1]), fmaxf(tmv[2], tmv[3]));
    float t1 = fmaxf(fmaxf(tmv[4], tmv[5]), fmaxf(tmv[6], tmv[7]));
    float tm = halfcomb_max(fmaxf(t0, t1));

    if (!__all(tm <= mraw + 64.f)) {  // T13 defer-max
      float mnew = fmaxf(mraw, tm);
      float alpha = __builtin_exp2f((mraw - mnew) * C);
      lsum *= alpha;
#pragma unroll
      for (int rr = 0; rr < 16; ++rr) {
        oacc[0][rr] *= alpha;
        oacc[1][rr] *= alpha;
      }
      mraw = mnew;
    }
    const float mC = mraw * C;
    float psum = 0.f;
#pragma unroll
    for (int rr = 0; rr < 16; ++rr) {
      float pp = __builtin_exp2f(__builtin_fmaf(sa[rr], C, -mC));
      sa[rr] = pp;
      psum += pp;
    }
    lsum += halfcomb_sum(psum);

    // ---- P^T -> bf16 B-frags + PV (verified attn4 mapping, single tile) --
    __builtin_amdgcn_s_setprio(1);
#pragma unroll
    for (int half = 0; half < 2; ++half) {
      const int rb = half * 8;
      unsigned a0 = pack2bf(sa[rb + 0], sa[rb + 1]);
      unsigned a1 = pack2bf(sa[rb + 2], sa[rb + 3]);
      unsigned b0w = pack2bf(sa[rb + 4], sa[rb + 5]);
      unsigned b1w = pack2bf(sa[rb + 6], sa[rb + 7]);
      union { unsigned u[4]; bf16x8 v; } pf;
#ifdef HAVE_PL32
      pl32sw(a0, b0w);
      pl32sw(a1, b1w);
      pf.u[0] = a0; pf.u[1] = a1; pf.u[2] = b0w; pf.u[3] = b1w;
#else
      unsigned xa0 = __shfl_xor(a0, 32, 64);
      unsigned xa1 = __shfl_xor(a1, 32, 64);
      unsigned xb0 = __shfl_xor(b0w, 32, 64);
      unsigned xb1 = __shfl_xor(b1w, 32, 64);
      pf.u[0] = lo_half ? a0 : xb0;
      pf.u[1] = lo_half ? a1 : xb1;
      pf.u[2] = lo_half ? xa0 : b0w;
      pf.u[3] = lo_half ? xa1 : b1w;
#endif
      oacc[0] = __builtin_amdgcn_mfma_f32_32x32x16_bf16(vf[0][half], pf.v,
                                                        oacc[0], 0, 0, 0);
      oacc[1] = __builtin_amdgcn_mfma_f32_32x32x16_bf16(vf[1][half], pf.v,
                                                        oacc[1], 0, 0, 0);
    }
    __builtin_amdgcn_s_setprio(0);

    VMWAIT0;   // next-tile stage landed; safe to read buf^1 / overwrite buf
    buf ^= 1;
  }

  // ---- epilogue: ctx[b][qrow][h*64+hd] = oacc^T / lsum ----
  const float linv = 1.0f / lsum;
  ushort* crow = &ctx[((size_t)(b * S_LEN) + qrow) * DMODEL + h * HDIM];
#pragma unroll
  for (int t2 = 0; t2 < 2; ++t2)
#pragma unroll
    for (int g2 = 0; g2 < 4; ++g2) {
      ushort4 o;  // hd = t2*32 + g2*8 + hi*4 + rg
      o.x = f2bf(oacc[t2][g2 * 4 + 0] * linv);
      o.y = f2bf(oacc[t2][g2 * 4 + 1] * linv);
      o.z = f2bf(oacc[t2][g2 * 4 + 2] * linv);
      o.w = f2bf(oacc[t2][g2 * 4 + 3] * linv);
      *(ushort4*)&crow[t2 * 32 + g2 * 8 + hi * 4] = o;
    }
}

// ---------------- launch ----------------

extern "C" void kernel_launch(void* const* d_in, const int* in_sizes, int n_in,
                              void* d_out, int out_size, void* d_ws,
                              size_t ws_size, hipStream_t stream) {
  const float* x  = (const float*)d_in[0];
  const float* Wq = (const float*)d_in[1];
  const float* bq = (const float*)d_in[2];
  const float* Wk = (const float*)d_in[3];
  const float* bk = (const float*)d_in[4];
  const float* Wv = (const float*)d_in[5];
  const float* bv = (const float*)d_in[6];
  const float* Wo = (const float*)d_in[7];
  const float* bo = (const float*)d_in[8];

  char* ws = (char*)d_ws;
  ushort* Xbf = (ushort*)ws;                               // 8 MB
  ushort* WT  = (ushort*)(ws + (size_t)8 * 1024 * 1024);   // 8 MB
  ushort* QKV = (ushort*)(ws + (size_t)16 * 1024 * 1024);  // Q,K then Vt
  ushort* CTX = (ushort*)(ws + (size_t)40 * 1024 * 1024);  // V-rowmajor, ctx

  const size_t QKV_ELEMS = (size_t)MROWS * DMODEL;  // 4 M elems = 8 MB
  const size_t W_ELEMS = (size_t)DMODEL * DMODEL;

  ushort* Qp  = QKV;                  // [B,H,S,HD]
  ushort* Kp  = QKV + QKV_ELEMS;      // [B,H,S,HD]
  ushort* Vtp = QKV + 2 * QKV_ELEMS;  // [B,H,HD,S]  (trV output)
  ushort* Vrp = CTX;                  // [B,H,S,HD]  (gemm256 scratch out)

  cvt_x<<<4096, 256, 0, stream>>>(x, Xbf);
  cvt_wt<<<dim3(16, 16, 4), 256, 0, stream>>>(Wq, Wk, Wv, Wo, WT);
  gemm256<<<dim3(16, 16), 512, 0, stream>>>(Xbf, WT, bq, bk, bv, Qp, Kp, Vrp);
  trV<<<dim3(64, 2, 32), 256, 0, stream>>>(Vrp, Vtp);
  attn6<<<dim3(512), 256, 0, stream>>>(Qp, Kp, Vtp, CTX);
  gemm128o<<<dim3(32, 8), 256, 0, stream>>>(CTX, WT + 3 * W_ELEMS, bo,
                                            (float*)d_out);
}

// Round 15
// 160.520 us; speedup vs baseline: 1.0310x; 1.0310x over previous
//
#include <hip/hip_runtime.h>

// MHA: B=2, S=2048, D=1024, H=16, HD=64, causal, scale=1/8.
// Round 15: revert failed attn6; attn7 = attn3's verified 2-wave/64-row-tile
// structure + attn4's verified math (permlane pack, fmax tree, defer-max),
// 32KB LDS -> 5 blocks/CU (10 waves/CU), grid 1024 (one tile per block,
// heavy-first, XCD-chunked). gemm256 / gemm128o / converts = round 13.
//   ws layout (bytes):
//     [0,8M)    Xbf  : x as bf16 [4096,1024]
//     [8M,16M)  WT   : WqT,WkT,WvT,WoT bf16 [1024,1024] each ([N][K])
//     [16M,32M) Q,K  : [B,H,S,HD] bf16
//     [32M,40M) Vt   : [B,H,HD,S] bf16 (written by trV)
//     [40M,48M) CTX  : first V row-major (gemm256 out), then ctx [B,S,D]

#define S_LEN 2048
#define DMODEL 1024
#define NHEAD 16
#define HDIM 64
#define MROWS 4096  // B*S

typedef __bf16 bf16x8 __attribute__((ext_vector_type(8)));
typedef float f32x4 __attribute__((ext_vector_type(4)));
typedef float f32x16 __attribute__((ext_vector_type(16)));

__device__ __forceinline__ ushort f2bf(float f) {
  union { float f; unsigned u; } v; v.f = f;
  unsigned r = v.u + 0x7fffu + ((v.u >> 16) & 1u);  // RNE
  return (ushort)(r >> 16);
}

__device__ __forceinline__ void gload_lds16(const ushort* g, ushort* l) {
  __builtin_amdgcn_global_load_lds(
      (const __attribute__((address_space(1))) void*)g,
      (__attribute__((address_space(3))) void*)l, 16, 0, 0);
}

// pack two f32 -> one dword of 2 bf16 (compiler emits v_cvt_pk_bf16_f32)
__device__ __forceinline__ unsigned pack2bf(float lo, float hi) {
  union { __bf16 h[2]; unsigned u; } t;
  t.h[0] = (__bf16)lo; t.h[1] = (__bf16)hi;
  return t.u;
}

#if __has_builtin(__builtin_amdgcn_permlane32_swap)
#define HAVE_PL32 1
// after call: a = {a.lo | b.lo}, b = {a.hi | b.hi}  (lane<32 | lane>=32)
__device__ __forceinline__ void pl32sw(unsigned& a, unsigned& b) {
  auto r = __builtin_amdgcn_permlane32_swap((int)a, (int)b, false, false);
  a = (unsigned)r[0];
  b = (unsigned)r[1];
}
#endif

__device__ __forceinline__ float halfcomb_max(float x) {
#ifdef HAVE_PL32
  unsigned a = __float_as_uint(x), b = a;
  pl32sw(a, b);
  return fmaxf(__uint_as_float(a), __uint_as_float(b));
#else
  return fmaxf(x, __shfl_xor(x, 32, 64));
#endif
}
__device__ __forceinline__ float halfcomb_sum(float x) {
#ifdef HAVE_PL32
  unsigned a = __float_as_uint(x), b = a;
  pl32sw(a, b);
  return __uint_as_float(a) + __uint_as_float(b);
#else
  return x + __shfl_xor(x, 32, 64);
#endif
}

// ---------------- conversion kernels ----------------

__global__ __launch_bounds__(256) void cvt_x(const float* __restrict__ x,
                                             ushort* __restrict__ xb) {
  int i = (blockIdx.x * 256 + threadIdx.x) * 4;
  float4 v = *(const float4*)&x[i];
  ushort4 o;
  o.x = f2bf(v.x); o.y = f2bf(v.y); o.z = f2bf(v.z); o.w = f2bf(v.w);
  *(ushort4*)&xb[i] = o;
}

// W [K][N] fp32 -> WT [N][K] bf16, 64x64 tiles, vectorized
__global__ __launch_bounds__(256) void cvt_wt(const float* __restrict__ W0,
                                              const float* __restrict__ W1,
                                              const float* __restrict__ W2,
                                              const float* __restrict__ W3,
                                              ushort* __restrict__ out) {
  const float* W = blockIdx.z == 0 ? W0 : blockIdx.z == 1 ? W1
                   : blockIdx.z == 2 ? W2 : W3;
  ushort* WT = out + (size_t)blockIdx.z * DMODEL * DMODEL;
  __shared__ float tile[64][65];
  const int n0 = blockIdx.x * 64, k0 = blockIdx.y * 64;
#pragma unroll
  for (int i = 0; i < 4; ++i) {
    int chunk = i * 256 + threadIdx.x;  // 0..1023
    int r = chunk >> 4, c4 = chunk & 15;
    float4 v = *(const float4*)&W[(size_t)(k0 + r) * DMODEL + n0 + c4 * 4];
    tile[r][c4 * 4 + 0] = v.x; tile[r][c4 * 4 + 1] = v.y;
    tile[r][c4 * 4 + 2] = v.z; tile[r][c4 * 4 + 3] = v.w;
  }
  __syncthreads();
#pragma unroll
  for (int i = 0; i < 4; ++i) {
    int chunk = i * 256 + threadIdx.x;
    int r = chunk >> 4, c4 = chunk & 15;
    ushort4 o;
    o.x = f2bf(tile[c4 * 4 + 0][r]); o.y = f2bf(tile[c4 * 4 + 1][r]);
    o.z = f2bf(tile[c4 * 4 + 2][r]); o.w = f2bf(tile[c4 * 4 + 3][r]);
    *(ushort4*)&WT[(size_t)(n0 + r) * DMODEL + k0 + c4 * 4] = o;
  }
}

// V [B,H,S,HD] -> Vt [B,H,HD,S], 32x32 LDS tiles
__global__ __launch_bounds__(256) void trV(const ushort* __restrict__ V,
                                           ushort* __restrict__ Vt) {
  const int bh = blockIdx.z;
  const ushort* src = V + (size_t)bh * S_LEN * HDIM;
  ushort* dst = Vt + (size_t)bh * HDIM * S_LEN;
  __shared__ ushort tile[32][33];
  int s0 = blockIdx.x * 32, h0 = blockIdx.y * 32;
  int tx = threadIdx.x & 31, ty = threadIdx.x >> 5;  // 32 x 8
#pragma unroll
  for (int i = 0; i < 32; i += 8)
    tile[ty + i][tx] = src[(size_t)(s0 + ty + i) * HDIM + h0 + tx];
  __syncthreads();
#pragma unroll
  for (int i = 0; i < 32; i += 8)
    dst[(size_t)(h0 + ty + i) * S_LEN + s0 + tx] = tile[tx][ty + i];
}

// ---------------- QKV GEMM: 256x192 tile, 8 waves, phase-paced ------------
__global__ __launch_bounds__(512) void gemm256(
    const ushort* __restrict__ A, const ushort* __restrict__ Bt,
    const float* __restrict__ b0, const float* __restrict__ b1,
    const float* __restrict__ b2, ushort* __restrict__ outQ,
    ushort* __restrict__ outK, ushort* __restrict__ outV) {
  const int flat = blockIdx.y * 16 + blockIdx.x;       // 0..255
  const int swz = (flat & 7) * 32 + (flat >> 3);       // bijective (256=8*32)
  const int bx = swz & 15, by = swz >> 4;
  const int m0 = bx * 256, n0 = by * 192;

  __shared__ __align__(16) ushort Al[2][256 * 64];  // 64 KB
  __shared__ __align__(16) ushort Bl[2][192 * 64];  // 48 KB

  const int tid = threadIdx.x;
  const int lane = tid & 63, wid = tid >> 6;
  const int wr = wid >> 2, wc = wid & 3;
  const int fr = lane & 15, hi16 = lane >> 4;

  f32x4 acc[8][3] = {};

#pragma unroll
  for (int l = 0; l < 4; ++l) {
    int chunk = l * 512 + tid;
    int row = chunk >> 3, cpos = chunk & 7;
    int scol = (cpos ^ (row & 7)) * 8;
    gload_lds16(&A[(size_t)(m0 + row) * DMODEL + scol], &Al[0][chunk * 8]);
  }
#pragma unroll
  for (int l = 0; l < 3; ++l) {
    int chunk = l * 512 + tid;
    int row = chunk >> 3, cpos = chunk & 7;
    int scol = (cpos ^ (row & 7)) * 8;
    gload_lds16(&Bt[(size_t)(n0 + row) * DMODEL + scol], &Bl[0][chunk * 8]);
  }
  __syncthreads();

  for (int t = 0; t < 16; ++t) {
    const int bt = t & 1;
    bf16x8 bfr[3];
#pragma unroll
    for (int s = 0; s < 4; ++s) {
      const int kk = s >> 1, mh = s & 1;
      bf16x8 af[4];
#pragma unroll
      for (int q = 0; q < 4; ++q) {
        int rl = wr * 128 + (mh * 4 + q) * 16 + fr;
        af[q] = *(const bf16x8*)&Al[bt][rl * 64 +
                                        ((kk * 4 + hi16) ^ (rl & 7)) * 8];
      }
      if (mh == 0) {
#pragma unroll
        for (int nf = 0; nf < 3; ++nf) {
          int rl = wc * 48 + nf * 16 + fr;
          bfr[nf] = *(const bf16x8*)&Bl[bt][rl * 64 +
                                            ((kk * 4 + hi16) ^ (rl & 7)) * 8];
        }
      }
      if (t + 1 < 16 && s < 2) {
        const int k64 = (t + 1) * 64;
        if (s == 0) {
#pragma unroll
          for (int l = 0; l < 4; ++l) {
            int chunk = l * 512 + tid;
            int row = chunk >> 3, cpos = chunk & 7;
            int scol = (cpos ^ (row & 7)) * 8;
            gload_lds16(&A[(size_t)(m0 + row) * DMODEL + k64 + scol],
                        &Al[bt ^ 1][chunk * 8]);
          }
        } else {
#pragma unroll
          for (int l = 0; l < 3; ++l) {
            int chunk = l * 512 + tid;
            int row = chunk >> 3, cpos = chunk & 7;
            int scol = (cpos ^ (row & 7)) * 8;
            gload_lds16(&Bt[(size_t)(n0 + row) * DMODEL + k64 + scol],
                        &Bl[bt ^ 1][chunk * 8]);
          }
        }
      }
      __builtin_amdgcn_s_barrier();
      __builtin_amdgcn_s_setprio(1);
#pragma unroll
      for (int q = 0; q < 4; ++q)
#pragma unroll
        for (int nf = 0; nf < 3; ++nf)
          acc[mh * 4 + q][nf] = __builtin_amdgcn_mfma_f32_16x16x32_bf16(
              af[q], bfr[nf], acc[mh * 4 + q][nf], 0, 0, 0);
      __builtin_amdgcn_s_setprio(0);
      if (s < 3) __builtin_amdgcn_s_barrier();
    }
    __syncthreads();
  }

#pragma unroll
  for (int mf = 0; mf < 8; ++mf) {
#pragma unroll
    for (int nf = 0; nf < 3; ++nf) {
      int col = n0 + wc * 48 + nf * 16 + fr;
      int z = col >> 10, cw = col & 1023;
      float bval = z == 0 ? b0[cw] : z == 1 ? b1[cw] : b2[cw];
      int h = cw >> 6, hd = cw & (HDIM - 1);
      ushort* dst = (z == 0) ? outQ : (z == 1) ? outK : outV;
#pragma unroll
      for (int rg = 0; rg < 4; ++rg) {
        int row = m0 + wr * 128 + mf * 16 + hi16 * 4 + rg;
        int b = row >> 11, sq = row & (S_LEN - 1);
        float val = acc[mf][nf][rg] + bval;
        dst[(((size_t)(b * NHEAD + h)) * S_LEN + sq) * HDIM + hd] = f2bf(val);
      }
    }
  }
}

// ---------------- out-proj GEMM (128x128 tile, BK=64, 2-phase dbuf) -------
__global__ __launch_bounds__(256) void gemm128o(
    const ushort* __restrict__ A, const ushort* __restrict__ Bt,
    const float* __restrict__ b0, float* __restrict__ outB) {
  const int NT = 256;
  const int flat = blockIdx.y * 32 + blockIdx.x;
  const int swz = (flat & 7) * (NT >> 3) + (flat >> 3);
  const int bx = swz & 31, by = swz >> 5;
  const int m0 = bx * 128, n0 = by * 128;

  __shared__ __align__(16) ushort Alds[2][128 * 64];
  __shared__ __align__(16) ushort Blds[2][128 * 64];

  const int tid = threadIdx.x;
  const int lane = tid & 63, w = tid >> 6;
  const int wr = w >> 1, wc = w & 1;
  const int fr = lane & 15, hi16 = lane >> 4;

  f32x4 acc[4][4] = {};

  auto STAGE = [&](int kt, int bi) {
#pragma unroll
    for (int it = 0; it < 4; ++it) {
      int c = it * 256 + tid;
      int row = c >> 3;
      int sc = ((c & 7) ^ (row & 7)) * 8;
      int ldsbase = (it * 256 + w * 64) * 8;
      gload_lds16(&A[(size_t)(m0 + row) * DMODEL + kt + sc],
                  &Alds[bi][ldsbase]);
      gload_lds16(&Bt[(size_t)(n0 + row) * DMODEL + kt + sc],
                  &Blds[bi][ldsbase]);
    }
  };

  auto COMPUTE = [&](int bi) {
#pragma unroll
    for (int kk = 0; kk < 2; ++kk) {
      bf16x8 af[4], bfr[4];
#pragma unroll
      for (int i = 0; i < 4; ++i) {
        int row = wr * 64 + i * 16 + fr;
        af[i] = *(const bf16x8*)&Alds[bi][row * 64 +
                                          ((kk * 4 + hi16) ^ (row & 7)) * 8];
      }
#pragma unroll
      for (int j = 0; j < 4; ++j) {
        int row = wc * 64 + j * 16 + fr;
        bfr[j] = *(const bf16x8*)&Blds[bi][row * 64 +
                                           ((kk * 4 + hi16) ^ (row & 7)) * 8];
      }
#pragma unroll
      for (int i = 0; i < 4; ++i)
#pragma unroll
        for (int j = 0; j < 4; ++j)
          acc[i][j] = __builtin_amdgcn_mfma_f32_16x16x32_bf16(af[i], bfr[j],
                                                              acc[i][j], 0, 0, 0);
    }
  };

  STAGE(0, 0);
  __syncthreads();
  int buf = 0;
  for (int kt = 64; kt < DMODEL; kt += 64) {
    STAGE(kt, buf ^ 1);
    COMPUTE(buf);
    __syncthreads();
    buf ^= 1;
  }
  COMPUTE(buf);

#pragma unroll
  for (int i = 0; i < 4; ++i) {
#pragma unroll
    for (int j = 0; j < 4; ++j) {
      int col = n0 + wc * 64 + j * 16 + fr;
      float bval = b0[col];
#pragma unroll
      for (int r = 0; r < 4; ++r) {
        int row = m0 + wr * 64 + i * 16 + hi16 * 4 + r;
        outB[(size_t)row * DMODEL + col] = acc[i][j][r] + bval;
      }
    }
  }
}

// ---------------- flash attention (causal): 2-wave blocks, 1 tile each ----
// 1024 blocks x 128 thr. Block owns one 64-row q-tile j (wq splits rows);
// dbuf K/V LDS (32 KB -> 5 blocks/CU = 10 waves/CU). Heavy-first dispatch,
// XCD-chunked (4 heads per XCD). Math = verified attn4 blocks.
__global__ __launch_bounds__(128) void attn7(const ushort* __restrict__ Q,
                                             const ushort* __restrict__ K,
                                             const ushort* __restrict__ Vt,
                                             ushort* __restrict__ ctx) {
  const int blk = blockIdx.x;
  const int w = (blk & 7) * 128 + (blk >> 3);  // chunked XCD id (1024=8*128)
  const int bh = w >> 5;                       // 4 heads per XCD chunk
  const int j = 31 - (w & 31);                 // 64-row tile, heavy first
  const int b = bh >> 4, h = bh & 15;
  const int tid = threadIdx.x;
  const int lane = tid & 63, wq = tid >> 6;
  const int q32 = lane & 31, hi = lane >> 5;
  const bool lo_half = (hi == 0);
  const int qbase = j * 64 + wq * 32;
  const int qrow = qbase + q32;

  const ushort* Qb = Q + (size_t)bh * S_LEN * HDIM;
  const ushort* Kb = K + (size_t)bh * S_LEN * HDIM;
  const ushort* Vb = Vt + (size_t)bh * HDIM * S_LEN;

  __shared__ __align__(16) ushort Kl[2][64 * 64];  // 16 KB
  __shared__ __align__(16) ushort Vl[2][64 * 64];  // 16 KB

  const float C = 0.125f * 1.44269504f;  // scale * log2(e)

  bf16x8 qf[4];
#pragma unroll
  for (int s = 0; s < 4; ++s)
    qf[s] = *(const bf16x8*)&Qb[(size_t)qrow * HDIM + s * 16 + hi * 8];

  f32x16 oacc[2] = {};
  float mraw = -1e30f, lsum = 0.f;
  const int nstep = j + 1;

  // prologue: stage step 0 into buf 0 (linear dest, inverse-swz source)
#pragma unroll
  for (int it = 0; it < 4; ++it) {
    int chunk = it * 128 + tid;
    int row = chunk >> 3, sc = ((chunk & 7) ^ (row & 7)) * 8;
    gload_lds16(&Kb[(size_t)row * HDIM + sc], &Kl[0][chunk * 8]);
    gload_lds16(&Vb[(size_t)row * S_LEN + sc], &Vl[0][chunk * 8]);
  }
  __syncthreads();  // drains vmcnt(0)

  for (int step = 0; step < nstep; ++step) {
    const int bi = step & 1;
    const int kv0 = step * 64;
    // issue next-tile stage first (overlaps compute)
    if (step + 1 < nstep) {
      const int kvn = kv0 + 64;
#pragma unroll
      for (int it = 0; it < 4; ++it) {
        int chunk = it * 128 + tid;
        int row = chunk >> 3, sc = ((chunk & 7) ^ (row & 7)) * 8;
        gload_lds16(&Kb[(size_t)(kvn + row) * HDIM + sc],
                    &Kl[bi ^ 1][chunk * 8]);
        gload_lds16(&Vb[(size_t)row * S_LEN + kvn + sc],
                    &Vl[bi ^ 1][chunk * 8]);
      }
    }

    // ---- QK^T: S^T[k][q], 2 tiles of 32 k ----
    f32x16 sa[2] = {};
    __builtin_amdgcn_s_setprio(1);
#pragma unroll
    for (int t = 0; t < 2; ++t) {
      const int row = t * 32 + q32;
      const int rsw = (row & 7);
#pragma unroll
      for (int sl = 0; sl < 4; ++sl) {
        bf16x8 kf = *(const bf16x8*)&Kl[bi][row * 64 + ((sl * 2 + hi) ^ rsw) * 8];
        sa[t] = __builtin_amdgcn_mfma_f32_32x32x16_bf16(kf, qf[sl], sa[t],
                                                        0, 0, 0);
      }
    }
    __builtin_amdgcn_s_setprio(0);

    // ---- V^T A-frags from LDS ----
    bf16x8 vf[2][4];
#pragma unroll
    for (int t2 = 0; t2 < 2; ++t2) {
      const int row = t2 * 32 + q32;
      const int rsw = (row & 7);
#pragma unroll
      for (int sl = 0; sl < 4; ++sl)
        vf[t2][sl] = *(const bf16x8*)&Vl[bi][row * 64 + ((sl * 2 + hi) ^ rsw) * 8];
    }

    // ---- causal mask (final step only; wave-uniform branch) ----
    if (kv0 + 63 > qbase) {
      const int khi = kv0 + 4 * hi;
#pragma unroll
      for (int t = 0; t < 2; ++t)
#pragma unroll
        for (int rr = 0; rr < 16; ++rr) {
          int kg = khi + t * 32 + (rr & 3) + 8 * (rr >> 2);
          if (kg > qrow) sa[t][rr] = -1e30f;
        }
    }

    // ---- online softmax (raw domain; lane-local rows) ----
    float tmv[8];
#pragma unroll
    for (int rr = 0; rr < 8; ++rr)
      tmv[rr] = fmaxf(fmaxf(sa[0][rr], sa[0][rr + 8]),
                      fmaxf(sa[1][rr], sa[1][rr + 8]));
    float t0 = fmaxf(fmaxf(tmv[0], tmv[1]), fmaxf(tmv[2], tmv[3]));
    float t1 = fmaxf(fmaxf(tmv[4], tmv[5]), fmaxf(tmv[6], tmv[7]));
    float tm = halfcomb_max(fmaxf(t0, t1));

    if (!__all(tm <= mraw + 64.f)) {  // T13 defer-max
      float mnew = fmaxf(mraw, tm);
      float alpha = __builtin_exp2f((mraw - mnew) * C);
      lsum *= alpha;
#pragma unroll
      for (int rr = 0; rr < 16; ++rr) {
        oacc[0][rr] *= alpha;
        oacc[1][rr] *= alpha;
      }
      mraw = mnew;
    }
    const float mC = mraw * C;
    float psum = 0.f;
#pragma unroll
    for (int t = 0; t < 2; ++t)
#pragma unroll
      for (int rr = 0; rr < 16; ++rr) {
        float pp = __builtin_exp2f(__builtin_fmaf(sa[t][rr], C, -mC));
        sa[t][rr] = pp;
        psum += pp;
      }
    lsum += halfcomb_sum(psum);

    // ---- P^T -> bf16 B-frags + PV ----
    __builtin_amdgcn_s_setprio(1);
#pragma unroll
    for (int t = 0; t < 2; ++t) {
#pragma unroll
      for (int half = 0; half < 2; ++half) {
        const int rb = half * 8;
        unsigned a0 = pack2bf(sa[t][rb + 0], sa[t][rb + 1]);
        unsigned a1 = pack2bf(sa[t][rb + 2], sa[t][rb + 3]);
        unsigned b0w = pack2bf(sa[t][rb + 4], sa[t][rb + 5]);
        unsigned b1w = pack2bf(sa[t][rb + 6], sa[t][rb + 7]);
        union { unsigned u[4]; bf16x8 v; } pf;
#ifdef HAVE_PL32
        pl32sw(a0, b0w);
        pl32sw(a1, b1w);
        pf.u[0] = a0; pf.u[1] = a1; pf.u[2] = b0w; pf.u[3] = b1w;
#else
        unsigned xa0 = __shfl_xor(a0, 32, 64);
        unsigned xa1 = __shfl_xor(a1, 32, 64);
        unsigned xb0 = __shfl_xor(b0w, 32, 64);
        unsigned xb1 = __shfl_xor(b1w, 32, 64);
        pf.u[0] = lo_half ? a0 : xb0;
        pf.u[1] = lo_half ? a1 : xb1;
        pf.u[2] = lo_half ? xa0 : b0w;
        pf.u[3] = lo_half ? xa1 : b1w;
#endif
        oacc[0] = __builtin_amdgcn_mfma_f32_32x32x16_bf16(
            vf[0][t * 2 + half], pf.v, oacc[0], 0, 0, 0);
        oacc[1] = __builtin_amdgcn_mfma_f32_32x32x16_bf16(
            vf[1][t * 2 + half], pf.v, oacc[1], 0, 0, 0);
      }
    }
    __builtin_amdgcn_s_setprio(0);

    __syncthreads();  // stage complete (vmcnt 0) + reads done before overwrite
  }

  // ---- epilogue: ctx[b][qrow][h*64+hd] = oacc^T / lsum ----
  const float linv = 1.0f / lsum;
  ushort* crow = &ctx[((size_t)(b * S_LEN) + qrow) * DMODEL + h * HDIM];
#pragma unroll
  for (int t = 0; t < 2; ++t)
#pragma unroll
    for (int g2 = 0; g2 < 4; ++g2) {
      ushort4 o;  // hd = t*32 + g2*8 + hi*4 + r
      o.x = f2bf(oacc[t][g2 * 4 + 0] * linv);
      o.y = f2bf(oacc[t][g2 * 4 + 1] * linv);
      o.z = f2bf(oacc[t][g2 * 4 + 2] * linv);
      o.w = f2bf(oacc[t][g2 * 4 + 3] * linv);
      *(ushort4*)&crow[t * 32 + g2 * 8 + hi * 4] = o;
    }
}

// ---------------- launch ----------------

extern "C" void kernel_launch(void* const* d_in, const int* in_sizes, int n_in,
                              void* d_out, int out_size, void* d_ws,
                              size_t ws_size, hipStream_t stream) {
  const float* x  = (const float*)d_in[0];
  const float* Wq = (const float*)d_in[1];
  const float* bq = (const float*)d_in[2];
  const float* Wk = (const float*)d_in[3];
  const float* bk = (const float*)d_in[4];
  const float* Wv = (const float*)d_in[5];
  const float* bv = (const float*)d_in[6];
  const float* Wo = (const float*)d_in[7];
  const float* bo = (const float*)d_in[8];

  char* ws = (char*)d_ws;
  ushort* Xbf = (ushort*)ws;                               // 8 MB
  ushort* WT  = (ushort*)(ws + (size_t)8 * 1024 * 1024);   // 8 MB
  ushort* QKV = (ushort*)(ws + (size_t)16 * 1024 * 1024);  // Q,K then Vt
  ushort* CTX = (ushort*)(ws + (size_t)40 * 1024 * 1024);  // V-rowmajor, ctx

  const size_t QKV_ELEMS = (size_t)MROWS * DMODEL;  // 4 M elems = 8 MB
  const size_t W_ELEMS = (size_t)DMODEL * DMODEL;

  ushort* Qp  = QKV;                  // [B,H,S,HD]
  ushort* Kp  = QKV + QKV_ELEMS;      // [B,H,S,HD]
  ushort* Vtp = QKV + 2 * QKV_ELEMS;  // [B,H,HD,S]  (trV output)
  ushort* Vrp = CTX;                  // [B,H,S,HD]  (gemm256 scratch out)

  cvt_x<<<4096, 256, 0, stream>>>(x, Xbf);
  cvt_wt<<<dim3(16, 16, 4), 256, 0, stream>>>(Wq, Wk, Wv, Wo, WT);
  gemm256<<<dim3(16, 16), 512, 0, stream>>>(Xbf, WT, bq, bk, bv, Qp, Kp, Vrp);
  trV<<<dim3(64, 2, 32), 256, 0, stream>>>(Vrp, Vtp);
  attn7<<<dim3(1024), 128, 0, stream>>>(Qp, Kp, Vtp, CTX);
  gemm128o<<<dim3(32, 8), 256, 0, stream>>>(CTX, WT + 3 * W_ELEMS, bo,
                                            (float*)d_out);
}

// Round 16
// 120.149 us; speedup vs baseline: 1.3774x; 1.3360x over previous
//
#include <hip/hip_runtime.h>

// MHA: B=2, S=2048, D=1024, H=16, HD=64, causal, scale=1/8.
// Round 16: REVERT attention to verified attn4 (attn6/attn7 experiments both
// regressed — post-mortem: full-residency grids freeze imbalance unless
// per-block work is uniform; attn4's j/31-j pairing provides that).
// One change vs round 13: gemm128o now uses the gemm256-proven 4-sub-phase
// pacing (early half-stage, raw barriers, setprio MFMA clusters).
//   ws layout (bytes):
//     [0,8M)    Xbf  : x as bf16 [4096,1024]
//     [8M,16M)  WT   : WqT,WkT,WvT,WoT bf16 [1024,1024] each ([N][K])
//     [16M,32M) Q,K  : [B,H,S,HD] bf16
//     [32M,40M) Vt   : [B,H,HD,S] bf16 (written by trV)
//     [40M,48M) CTX  : first V row-major (gemm256 out), then ctx [B,S,D]

#define S_LEN 2048
#define DMODEL 1024
#define NHEAD 16
#define HDIM 64
#define MROWS 4096  // B*S

typedef __bf16 bf16x8 __attribute__((ext_vector_type(8)));
typedef float f32x4 __attribute__((ext_vector_type(4)));
typedef float f32x16 __attribute__((ext_vector_type(16)));

__device__ __forceinline__ ushort f2bf(float f) {
  union { float f; unsigned u; } v; v.f = f;
  unsigned r = v.u + 0x7fffu + ((v.u >> 16) & 1u);  // RNE
  return (ushort)(r >> 16);
}

__device__ __forceinline__ void gload_lds16(const ushort* g, ushort* l) {
  __builtin_amdgcn_global_load_lds(
      (const __attribute__((address_space(1))) void*)g,
      (__attribute__((address_space(3))) void*)l, 16, 0, 0);
}

// pack two f32 -> one dword of 2 bf16 (compiler emits v_cvt_pk_bf16_f32)
__device__ __forceinline__ unsigned pack2bf(float lo, float hi) {
  union { __bf16 h[2]; unsigned u; } t;
  t.h[0] = (__bf16)lo; t.h[1] = (__bf16)hi;
  return t.u;
}

#if __has_builtin(__builtin_amdgcn_permlane32_swap)
#define HAVE_PL32 1
// after call: a = {a.lo | b.lo}, b = {a.hi | b.hi}  (lane<32 | lane>=32)
__device__ __forceinline__ void pl32sw(unsigned& a, unsigned& b) {
  auto r = __builtin_amdgcn_permlane32_swap((int)a, (int)b, false, false);
  a = (unsigned)r[0];
  b = (unsigned)r[1];
}
#endif

__device__ __forceinline__ float halfcomb_max(float x) {
#ifdef HAVE_PL32
  unsigned a = __float_as_uint(x), b = a;
  pl32sw(a, b);
  return fmaxf(__uint_as_float(a), __uint_as_float(b));
#else
  return fmaxf(x, __shfl_xor(x, 32, 64));
#endif
}
__device__ __forceinline__ float halfcomb_sum(float x) {
#ifdef HAVE_PL32
  unsigned a = __float_as_uint(x), b = a;
  pl32sw(a, b);
  return __uint_as_float(a) + __uint_as_float(b);
#else
  return x + __shfl_xor(x, 32, 64);
#endif
}

// ---------------- conversion kernels ----------------

__global__ __launch_bounds__(256) void cvt_x(const float* __restrict__ x,
                                             ushort* __restrict__ xb) {
  int i = (blockIdx.x * 256 + threadIdx.x) * 4;
  float4 v = *(const float4*)&x[i];
  ushort4 o;
  o.x = f2bf(v.x); o.y = f2bf(v.y); o.z = f2bf(v.z); o.w = f2bf(v.w);
  *(ushort4*)&xb[i] = o;
}

// W [K][N] fp32 -> WT [N][K] bf16, 64x64 tiles, vectorized
__global__ __launch_bounds__(256) void cvt_wt(const float* __restrict__ W0,
                                              const float* __restrict__ W1,
                                              const float* __restrict__ W2,
                                              const float* __restrict__ W3,
                                              ushort* __restrict__ out) {
  const float* W = blockIdx.z == 0 ? W0 : blockIdx.z == 1 ? W1
                   : blockIdx.z == 2 ? W2 : W3;
  ushort* WT = out + (size_t)blockIdx.z * DMODEL * DMODEL;
  __shared__ float tile[64][65];
  const int n0 = blockIdx.x * 64, k0 = blockIdx.y * 64;
#pragma unroll
  for (int i = 0; i < 4; ++i) {
    int chunk = i * 256 + threadIdx.x;  // 0..1023
    int r = chunk >> 4, c4 = chunk & 15;
    float4 v = *(const float4*)&W[(size_t)(k0 + r) * DMODEL + n0 + c4 * 4];
    tile[r][c4 * 4 + 0] = v.x; tile[r][c4 * 4 + 1] = v.y;
    tile[r][c4 * 4 + 2] = v.z; tile[r][c4 * 4 + 3] = v.w;
  }
  __syncthreads();
#pragma unroll
  for (int i = 0; i < 4; ++i) {
    int chunk = i * 256 + threadIdx.x;
    int r = chunk >> 4, c4 = chunk & 15;
    ushort4 o;
    o.x = f2bf(tile[c4 * 4 + 0][r]); o.y = f2bf(tile[c4 * 4 + 1][r]);
    o.z = f2bf(tile[c4 * 4 + 2][r]); o.w = f2bf(tile[c4 * 4 + 3][r]);
    *(ushort4*)&WT[(size_t)(n0 + r) * DMODEL + k0 + c4 * 4] = o;
  }
}

// V [B,H,S,HD] -> Vt [B,H,HD,S], 32x32 LDS tiles
__global__ __launch_bounds__(256) void trV(const ushort* __restrict__ V,
                                           ushort* __restrict__ Vt) {
  const int bh = blockIdx.z;
  const ushort* src = V + (size_t)bh * S_LEN * HDIM;
  ushort* dst = Vt + (size_t)bh * HDIM * S_LEN;
  __shared__ ushort tile[32][33];
  int s0 = blockIdx.x * 32, h0 = blockIdx.y * 32;
  int tx = threadIdx.x & 31, ty = threadIdx.x >> 5;  // 32 x 8
#pragma unroll
  for (int i = 0; i < 32; i += 8)
    tile[ty + i][tx] = src[(size_t)(s0 + ty + i) * HDIM + h0 + tx];
  __syncthreads();
#pragma unroll
  for (int i = 0; i < 32; i += 8)
    dst[(size_t)(h0 + ty + i) * S_LEN + s0 + tx] = tile[tx][ty + i];
}

// ---------------- QKV GEMM: 256x192 tile, 8 waves, phase-paced ------------
__global__ __launch_bounds__(512) void gemm256(
    const ushort* __restrict__ A, const ushort* __restrict__ Bt,
    const float* __restrict__ b0, const float* __restrict__ b1,
    const float* __restrict__ b2, ushort* __restrict__ outQ,
    ushort* __restrict__ outK, ushort* __restrict__ outV) {
  const int flat = blockIdx.y * 16 + blockIdx.x;       // 0..255
  const int swz = (flat & 7) * 32 + (flat >> 3);       // bijective (256=8*32)
  const int bx = swz & 15, by = swz >> 4;
  const int m0 = bx * 256, n0 = by * 192;

  __shared__ __align__(16) ushort Al[2][256 * 64];  // 64 KB
  __shared__ __align__(16) ushort Bl[2][192 * 64];  // 48 KB

  const int tid = threadIdx.x;
  const int lane = tid & 63, wid = tid >> 6;
  const int wr = wid >> 2, wc = wid & 3;
  const int fr = lane & 15, hi16 = lane >> 4;

  f32x4 acc[8][3] = {};

#pragma unroll
  for (int l = 0; l < 4; ++l) {
    int chunk = l * 512 + tid;
    int row = chunk >> 3, cpos = chunk & 7;
    int scol = (cpos ^ (row & 7)) * 8;
    gload_lds16(&A[(size_t)(m0 + row) * DMODEL + scol], &Al[0][chunk * 8]);
  }
#pragma unroll
  for (int l = 0; l < 3; ++l) {
    int chunk = l * 512 + tid;
    int row = chunk >> 3, cpos = chunk & 7;
    int scol = (cpos ^ (row & 7)) * 8;
    gload_lds16(&Bt[(size_t)(n0 + row) * DMODEL + scol], &Bl[0][chunk * 8]);
  }
  __syncthreads();

  for (int t = 0; t < 16; ++t) {
    const int bt = t & 1;
    bf16x8 bfr[3];
#pragma unroll
    for (int s = 0; s < 4; ++s) {
      const int kk = s >> 1, mh = s & 1;
      bf16x8 af[4];
#pragma unroll
      for (int q = 0; q < 4; ++q) {
        int rl = wr * 128 + (mh * 4 + q) * 16 + fr;
        af[q] = *(const bf16x8*)&Al[bt][rl * 64 +
                                        ((kk * 4 + hi16) ^ (rl & 7)) * 8];
      }
      if (mh == 0) {
#pragma unroll
        for (int nf = 0; nf < 3; ++nf) {
          int rl = wc * 48 + nf * 16 + fr;
          bfr[nf] = *(const bf16x8*)&Bl[bt][rl * 64 +
                                            ((kk * 4 + hi16) ^ (rl & 7)) * 8];
        }
      }
      if (t + 1 < 16 && s < 2) {
        const int k64 = (t + 1) * 64;
        if (s == 0) {
#pragma unroll
          for (int l = 0; l < 4; ++l) {
            int chunk = l * 512 + tid;
            int row = chunk >> 3, cpos = chunk & 7;
            int scol = (cpos ^ (row & 7)) * 8;
            gload_lds16(&A[(size_t)(m0 + row) * DMODEL + k64 + scol],
                        &Al[bt ^ 1][chunk * 8]);
          }
        } else {
#pragma unroll
          for (int l = 0; l < 3; ++l) {
            int chunk = l * 512 + tid;
            int row = chunk >> 3, cpos = chunk & 7;
            int scol = (cpos ^ (row & 7)) * 8;
            gload_lds16(&Bt[(size_t)(n0 + row) * DMODEL + k64 + scol],
                        &Bl[bt ^ 1][chunk * 8]);
          }
        }
      }
      __builtin_amdgcn_s_barrier();
      __builtin_amdgcn_s_setprio(1);
#pragma unroll
      for (int q = 0; q < 4; ++q)
#pragma unroll
        for (int nf = 0; nf < 3; ++nf)
          acc[mh * 4 + q][nf] = __builtin_amdgcn_mfma_f32_16x16x32_bf16(
              af[q], bfr[nf], acc[mh * 4 + q][nf], 0, 0, 0);
      __builtin_amdgcn_s_setprio(0);
      if (s < 3) __builtin_amdgcn_s_barrier();
    }
    __syncthreads();
  }

#pragma unroll
  for (int mf = 0; mf < 8; ++mf) {
#pragma unroll
    for (int nf = 0; nf < 3; ++nf) {
      int col = n0 + wc * 48 + nf * 16 + fr;
      int z = col >> 10, cw = col & 1023;
      float bval = z == 0 ? b0[cw] : z == 1 ? b1[cw] : b2[cw];
      int h = cw >> 6, hd = cw & (HDIM - 1);
      ushort* dst = (z == 0) ? outQ : (z == 1) ? outK : outV;
#pragma unroll
      for (int rg = 0; rg < 4; ++rg) {
        int row = m0 + wr * 128 + mf * 16 + hi16 * 4 + rg;
        int b = row >> 11, sq = row & (S_LEN - 1);
        float val = acc[mf][nf][rg] + bval;
        dst[(((size_t)(b * NHEAD + h)) * S_LEN + sq) * HDIM + hd] = f2bf(val);
      }
    }
  }
}

// ---------------- out-proj GEMM (128x128 tile, BK=64, 4-sub-phase paced) --
__global__ __launch_bounds__(256) void gemm128o(
    const ushort* __restrict__ A, const ushort* __restrict__ Bt,
    const float* __restrict__ b0, float* __restrict__ outB) {
  const int NT = 256;
  const int flat = blockIdx.y * 32 + blockIdx.x;
  const int swz = (flat & 7) * (NT >> 3) + (flat >> 3);
  const int bx = swz & 31, by = swz >> 5;
  const int m0 = bx * 128, n0 = by * 128;

  __shared__ __align__(16) ushort Alds[2][128 * 64];
  __shared__ __align__(16) ushort Blds[2][128 * 64];

  const int tid = threadIdx.x;
  const int lane = tid & 63, w = tid >> 6;
  const int wr = w >> 1, wc = w & 1;
  const int fr = lane & 15, hi16 = lane >> 4;

  f32x4 acc[4][4] = {};

  // prologue: stage K-tile 0 (A and B) into buf 0
#pragma unroll
  for (int it = 0; it < 4; ++it) {
    int c = it * 256 + tid;
    int row = c >> 3;
    int sc = ((c & 7) ^ (row & 7)) * 8;
    gload_lds16(&A[(size_t)(m0 + row) * DMODEL + sc], &Alds[0][c * 8]);
    gload_lds16(&Bt[(size_t)(n0 + row) * DMODEL + sc], &Blds[0][c * 8]);
  }
  __syncthreads();

  for (int t = 0; t < 16; ++t) {
    const int bt = t & 1;
#pragma unroll
    for (int s = 0; s < 2; ++s) {  // kk sub-phases
      bf16x8 af[4], bfr[4];
#pragma unroll
      for (int i = 0; i < 4; ++i) {
        int row = wr * 64 + i * 16 + fr;
        af[i] = *(const bf16x8*)&Alds[bt][row * 64 +
                                          ((s * 4 + hi16) ^ (row & 7)) * 8];
      }
#pragma unroll
      for (int j = 0; j < 4; ++j) {
        int row = wc * 64 + j * 16 + fr;
        bfr[j] = *(const bf16x8*)&Blds[bt][row * 64 +
                                           ((s * 4 + hi16) ^ (row & 7)) * 8];
      }
      // stage K-tile t+1 early: A at s=0, B at s=1
      if (t + 1 < 16) {
        const int k64 = (t + 1) * 64;
#pragma unroll
        for (int it = 0; it < 4; ++it) {
          int c = it * 256 + tid;
          int row = c >> 3;
          int sc = ((c & 7) ^ (row & 7)) * 8;
          if (s == 0)
            gload_lds16(&A[(size_t)(m0 + row) * DMODEL + k64 + sc],
                        &Alds[bt ^ 1][c * 8]);
          else
            gload_lds16(&Bt[(size_t)(n0 + row) * DMODEL + k64 + sc],
                        &Blds[bt ^ 1][c * 8]);
        }
      }
      __builtin_amdgcn_s_barrier();  // pacing
      __builtin_amdgcn_s_setprio(1);
#pragma unroll
      for (int i = 0; i < 4; ++i)
#pragma unroll
        for (int j = 0; j < 4; ++j)
          acc[i][j] = __builtin_amdgcn_mfma_f32_16x16x32_bf16(af[i], bfr[j],
                                                              acc[i][j], 0, 0, 0);
      __builtin_amdgcn_s_setprio(0);
      if (s < 1) __builtin_amdgcn_s_barrier();
    }
    __syncthreads();  // tile reads done + stage drained
  }

#pragma unroll
  for (int i = 0; i < 4; ++i) {
#pragma unroll
    for (int j = 0; j < 4; ++j) {
      int col = n0 + wc * 64 + j * 16 + fr;
      float bval = b0[col];
#pragma unroll
      for (int r = 0; r < 4; ++r) {
        int row = m0 + wr * 64 + i * 16 + hi16 * 4 + r;
        outB[(size_t)row * DMODEL + col] = acc[i][j][r] + bval;
      }
    }
  }
}

// ---------------- flash attention (causal), split-KV 4-wave (verified) ----
__global__ __launch_bounds__(256, 2) void attn4(const ushort* __restrict__ Q,
                                                const ushort* __restrict__ K,
                                                const ushort* __restrict__ Vt,
                                                ushort* __restrict__ ctx) {
  const int n = blockIdx.x;
  const int v = (n & 7) * 64 + (n >> 3);  // bijective XCD-contiguous (512=8*64)
  const int ptile = v & 15, bh = v >> 4;
  const int b = bh >> 4, h = bh & 15;
  const int tid = threadIdx.x;
  const int lane = tid & 63, wid = tid >> 6;
  const int p = wid >> 1;        // KV-parity pair: 0 even steps, 1 odd
  const int wq = wid & 1;        // 32-row q-subtile within the 64-row tile
  const int q32 = lane & 31, hi = lane >> 5;
  const bool lo_half = (hi == 0);
  const int tid2 = tid & 127;    // pair-local thread id (2 waves = 128 thr)

  const ushort* Qb = Q + (size_t)bh * S_LEN * HDIM;
  const ushort* Kb = K + (size_t)bh * S_LEN * HDIM;
  const ushort* Vb = Vt + (size_t)bh * HDIM * S_LEN;

  __shared__ __align__(16) ushort Kl[2][2][64 * 64];  // [pair][buf] 32 KB
  __shared__ __align__(16) ushort Vl[2][2][64 * 64];  // 32 KB
  float* scr = (float*)&Kl[0][0][0];  // merge scratch overlay (post-loop only)

  const float C = 0.125f * 1.44269504f;  // scale * log2(e)

  for (int ph = 0; ph < 2; ++ph) {
    const int j = ph ? 31 - ptile : ptile;  // 64-row q-tile index, 0..31
    const int qbase = j * 64 + wq * 32;
    const int qrow = qbase + q32;

    bf16x8 qf[4];
#pragma unroll
    for (int s = 0; s < 4; ++s)
      qf[s] = *(const bf16x8*)&Qb[(size_t)qrow * HDIM + s * 16 + hi * 8];

    f32x16 oacc[2] = {};
    float mraw = -1e30f, lsum = 0.f;
    const int NS = (j >> 1) + 1;  // iterations (pair0 steps; pair1 <= this)

    // prologue: pair p stages its first step (s0 = p) into buf 0
    if (p <= j) {
      const int kv = p * 64;
#pragma unroll
      for (int it = 0; it < 4; ++it) {
        int chunk = it * 128 + tid2;
        int row = chunk >> 3, sc = ((chunk & 7) ^ (row & 7)) * 8;
        gload_lds16(&Kb[(size_t)(kv + row) * HDIM + sc], &Kl[p][0][chunk * 8]);
        gload_lds16(&Vb[(size_t)row * S_LEN + kv + sc], &Vl[p][0][chunk * 8]);
      }
    }
    __syncthreads();

    int buf = 0;
    for (int it = 0; it < NS; ++it) {
      const int s = 2 * it + p;      // my global KV step
      const int kv0 = s * 64;

      // issue my pair's next-tile stage (s+2) first — overlaps compute
      if (s + 2 <= j) {
        const int kvn = kv0 + 128;
#pragma unroll
        for (int st = 0; st < 4; ++st) {
          int chunk = st * 128 + tid2;
          int row = chunk >> 3, sc = ((chunk & 7) ^ (row & 7)) * 8;
          gload_lds16(&Kb[(size_t)(kvn + row) * HDIM + sc],
                      &Kl[p][buf ^ 1][chunk * 8]);
          gload_lds16(&Vb[(size_t)row * S_LEN + kvn + sc],
                      &Vl[p][buf ^ 1][chunk * 8]);
        }
      }

      if (s <= j) {
        // ---- QK^T: S^T[k][q], 2 tiles of 32 k ----
        f32x16 sa[2] = {};
        __builtin_amdgcn_s_setprio(1);
#pragma unroll
        for (int t = 0; t < 2; ++t) {
          const int row = t * 32 + q32;
          const int rsw = (row & 7);
#pragma unroll
          for (int sl = 0; sl < 4; ++sl) {
            bf16x8 kf = *(const bf16x8*)&Kl[p][buf][row * 64 +
                                                    ((sl * 2 + hi) ^ rsw) * 8];
            sa[t] = __builtin_amdgcn_mfma_f32_32x32x16_bf16(kf, qf[sl], sa[t],
                                                            0, 0, 0);
          }
        }
        __builtin_amdgcn_s_setprio(0);

        // ---- V^T A-frags from LDS ----
        bf16x8 vf[2][4];
#pragma unroll
        for (int t2 = 0; t2 < 2; ++t2) {
          const int row = t2 * 32 + q32;
          const int rsw = (row & 7);
#pragma unroll
          for (int sl = 0; sl < 4; ++sl)
            vf[t2][sl] = *(const bf16x8*)&Vl[p][buf][row * 64 +
                                                     ((sl * 2 + hi) ^ rsw) * 8];
        }

        // ---- causal mask (only step s == j masks; wave-uniform) ----
        if (kv0 + 63 > qbase) {
          const int khi = kv0 + 4 * hi;
#pragma unroll
          for (int t = 0; t < 2; ++t)
#pragma unroll
            for (int rr = 0; rr < 16; ++rr) {
              int kg = khi + t * 32 + (rr & 3) + 8 * (rr >> 2);
              if (kg > qrow) sa[t][rr] = -1e30f;
            }
        }

        // ---- online softmax (raw domain; lane-local rows) ----
        float tmv[8];
#pragma unroll
        for (int rr = 0; rr < 8; ++rr)
          tmv[rr] = fmaxf(fmaxf(sa[0][rr], sa[0][rr + 8]),
                          fmaxf(sa[1][rr], sa[1][rr + 8]));
        float t0 = fmaxf(fmaxf(tmv[0], tmv[1]), fmaxf(tmv[2], tmv[3]));
        float t1 = fmaxf(fmaxf(tmv[4], tmv[5]), fmaxf(tmv[6], tmv[7]));
        float tm = halfcomb_max(fmaxf(t0, t1));

        if (!__all(tm <= mraw + 64.f)) {  // T13 defer-max
          float mnew = fmaxf(mraw, tm);
          float alpha = __builtin_exp2f((mraw - mnew) * C);
          lsum *= alpha;
#pragma unroll
          for (int rr = 0; rr < 16; ++rr) {
            oacc[0][rr] *= alpha;
            oacc[1][rr] *= alpha;
          }
          mraw = mnew;
        }
        const float mC = mraw * C;
        float psum = 0.f;
#pragma unroll
        for (int t = 0; t < 2; ++t)
#pragma unroll
          for (int rr = 0; rr < 16; ++rr) {
            float pp = __builtin_exp2f(__builtin_fmaf(sa[t][rr], C, -mC));
            sa[t][rr] = pp;
            psum += pp;
          }
        lsum += halfcomb_sum(psum);

        // ---- P^T -> bf16 B-frags + PV ----
        __builtin_amdgcn_s_setprio(1);
#pragma unroll
        for (int t = 0; t < 2; ++t) {
#pragma unroll
          for (int half = 0; half < 2; ++half) {
            const int rb = half * 8;
            unsigned a0 = pack2bf(sa[t][rb + 0], sa[t][rb + 1]);
            unsigned a1 = pack2bf(sa[t][rb + 2], sa[t][rb + 3]);
            unsigned b0w = pack2bf(sa[t][rb + 4], sa[t][rb + 5]);
            unsigned b1w = pack2bf(sa[t][rb + 6], sa[t][rb + 7]);
            union { unsigned u[4]; bf16x8 v; } pf;
#ifdef HAVE_PL32
            pl32sw(a0, b0w);
            pl32sw(a1, b1w);
            pf.u[0] = a0; pf.u[1] = a1; pf.u[2] = b0w; pf.u[3] = b1w;
#else
            unsigned xa0 = __shfl_xor(a0, 32, 64);
            unsigned xa1 = __shfl_xor(a1, 32, 64);
            unsigned xb0 = __shfl_xor(b0w, 32, 64);
            unsigned xb1 = __shfl_xor(b1w, 32, 64);
            pf.u[0] = lo_half ? a0 : xb0;
            pf.u[1] = lo_half ? a1 : xb1;
            pf.u[2] = lo_half ? xa0 : b0w;
            pf.u[3] = lo_half ? xa1 : b1w;
#endif
            oacc[0] = __builtin_amdgcn_mfma_f32_32x32x16_bf16(
                vf[0][t * 2 + half], pf.v, oacc[0], 0, 0, 0);
            oacc[1] = __builtin_amdgcn_mfma_f32_32x32x16_bf16(
                vf[1][t * 2 + half], pf.v, oacc[1], 0, 0, 0);
          }
        }
        __builtin_amdgcn_s_setprio(0);
      }

      __syncthreads();  // stage complete + LDS reads done before overwrite
      buf ^= 1;
    }

    // ---- merge pair partials: pair1 publishes, pair0 merges + stores ----
    const int base = (wq * 64 + lane) * 37;  // stride-37: conflict-free
    if (p == 1) {
      scr[base + 0] = mraw;
      scr[base + 1] = lsum;
#pragma unroll
      for (int t = 0; t < 2; ++t)
#pragma unroll
        for (int rr = 0; rr < 16; ++rr) scr[base + 2 + t * 16 + rr] = oacc[t][rr];
    }
    __syncthreads();
    if (p == 0) {
      const float mB = scr[base + 0], lB = scr[base + 1];
      const float mS = fmaxf(mraw, mB);
      const float aA = __builtin_exp2f((mraw - mS) * C);
      const float aB = __builtin_exp2f((mB - mS) * C);
      const float lT = lsum * aA + lB * aB;
      const float linv = 1.0f / lT;
      ushort* crow = &ctx[((size_t)(b * S_LEN) + qrow) * DMODEL + h * HDIM];
#pragma unroll
      for (int t = 0; t < 2; ++t)
#pragma unroll
        for (int g2 = 0; g2 < 4; ++g2) {
          ushort4 o;  // hd = t*32 + g2*8 + hi*4 + r
          float m0 = oacc[t][g2 * 4 + 0] * aA + scr[base + 2 + t * 16 + g2 * 4 + 0] * aB;
          float m1 = oacc[t][g2 * 4 + 1] * aA + scr[base + 2 + t * 16 + g2 * 4 + 1] * aB;
          float m2 = oacc[t][g2 * 4 + 2] * aA + scr[base + 2 + t * 16 + g2 * 4 + 2] * aB;
          float m3 = oacc[t][g2 * 4 + 3] * aA + scr[base + 2 + t * 16 + g2 * 4 + 3] * aB;
          o.x = f2bf(m0 * linv); o.y = f2bf(m1 * linv);
          o.z = f2bf(m2 * linv); o.w = f2bf(m3 * linv);
          *(ushort4*)&crow[t * 32 + g2 * 8 + hi * 4] = o;
        }
    }
    __syncthreads();  // scratch reads done before next phase restages LDS
  }
}

// ---------------- launch ----------------

extern "C" void kernel_launch(void* const* d_in, const int* in_sizes, int n_in,
                              void* d_out, int out_size, void* d_ws,
                              size_t ws_size, hipStream_t stream) {
  const float* x  = (const float*)d_in[0];
  const float* Wq = (const float*)d_in[1];
  const float* bq = (const float*)d_in[2];
  const float* Wk = (const float*)d_in[3];
  const float* bk = (const float*)d_in[4];
  const float* Wv = (const float*)d_in[5];
  const float* bv = (const float*)d_in[6];
  const float* Wo = (const float*)d_in[7];
  const float* bo = (const float*)d_in[8];

  char* ws = (char*)d_ws;
  ushort* Xbf = (ushort*)ws;                               // 8 MB
  ushort* WT  = (ushort*)(ws + (size_t)8 * 1024 * 1024);   // 8 MB
  ushort* QKV = (ushort*)(ws + (size_t)16 * 1024 * 1024);  // Q,K then Vt
  ushort* CTX = (ushort*)(ws + (size_t)40 * 1024 * 1024);  // V-rowmajor, ctx

  const size_t QKV_ELEMS = (size_t)MROWS * DMODEL;  // 4 M elems = 8 MB
  const size_t W_ELEMS = (size_t)DMODEL * DMODEL;

  ushort* Qp  = QKV;                  // [B,H,S,HD]
  ushort* Kp  = QKV + QKV_ELEMS;      // [B,H,S,HD]
  ushort* Vtp = QKV + 2 * QKV_ELEMS;  // [B,H,HD,S]  (trV output)
  ushort* Vrp = CTX;                  // [B,H,S,HD]  (gemm256 scratch out)

  cvt_x<<<4096, 256, 0, stream>>>(x, Xbf);
  cvt_wt<<<dim3(16, 16, 4), 256, 0, stream>>>(Wq, Wk, Wv, Wo, WT);
  gemm256<<<dim3(16, 16), 512, 0, stream>>>(Xbf, WT, bq, bk, bv, Qp, Kp, Vrp);
  trV<<<dim3(64, 2, 32), 256, 0, stream>>>(Vrp, Vtp);
  attn4<<<dim3(512), 256, 0, stream>>>(Qp, Kp, Vtp, CTX);
  gemm128o<<<dim3(32, 8), 256, 0, stream>>>(CTX, WT + 3 * W_ELEMS, bo,
                                            (float*)d_out);
}

// Round 17
// 119.791 us; speedup vs baseline: 1.3815x; 1.0030x over previous
//
#include <hip/hip_runtime.h>

// MHA: B=2, S=2048, D=1024, H=16, HD=64, causal, scale=1/8.
// Round 17: attn4 ILP pass (register-only): (a) QK sa[0]/sa[1] MFMA chains
// interleaved (was sequential 4-deep then 4-deep); (b) PV accumulator split
// oaccA/oaccB (chain depth 4->2 per step), summed once per phase.
// Everything else byte-identical to round 16 (120.1 us).
//   ws layout (bytes):
//     [0,8M)    Xbf  : x as bf16 [4096,1024]
//     [8M,16M)  WT   : WqT,WkT,WvT,WoT bf16 [1024,1024] each ([N][K])
//     [16M,32M) Q,K  : [B,H,S,HD] bf16
//     [32M,40M) Vt   : [B,H,HD,S] bf16 (written by trV)
//     [40M,48M) CTX  : first V row-major (gemm256 out), then ctx [B,S,D]

#define S_LEN 2048
#define DMODEL 1024
#define NHEAD 16
#define HDIM 64
#define MROWS 4096  // B*S

typedef __bf16 bf16x8 __attribute__((ext_vector_type(8)));
typedef float f32x4 __attribute__((ext_vector_type(4)));
typedef float f32x16 __attribute__((ext_vector_type(16)));

__device__ __forceinline__ ushort f2bf(float f) {
  union { float f; unsigned u; } v; v.f = f;
  unsigned r = v.u + 0x7fffu + ((v.u >> 16) & 1u);  // RNE
  return (ushort)(r >> 16);
}

__device__ __forceinline__ void gload_lds16(const ushort* g, ushort* l) {
  __builtin_amdgcn_global_load_lds(
      (const __attribute__((address_space(1))) void*)g,
      (__attribute__((address_space(3))) void*)l, 16, 0, 0);
}

// pack two f32 -> one dword of 2 bf16 (compiler emits v_cvt_pk_bf16_f32)
__device__ __forceinline__ unsigned pack2bf(float lo, float hi) {
  union { __bf16 h[2]; unsigned u; } t;
  t.h[0] = (__bf16)lo; t.h[1] = (__bf16)hi;
  return t.u;
}

#if __has_builtin(__builtin_amdgcn_permlane32_swap)
#define HAVE_PL32 1
// after call: a = {a.lo | b.lo}, b = {a.hi | b.hi}  (lane<32 | lane>=32)
__device__ __forceinline__ void pl32sw(unsigned& a, unsigned& b) {
  auto r = __builtin_amdgcn_permlane32_swap((int)a, (int)b, false, false);
  a = (unsigned)r[0];
  b = (unsigned)r[1];
}
#endif

__device__ __forceinline__ float halfcomb_max(float x) {
#ifdef HAVE_PL32
  unsigned a = __float_as_uint(x), b = a;
  pl32sw(a, b);
  return fmaxf(__uint_as_float(a), __uint_as_float(b));
#else
  return fmaxf(x, __shfl_xor(x, 32, 64));
#endif
}
__device__ __forceinline__ float halfcomb_sum(float x) {
#ifdef HAVE_PL32
  unsigned a = __float_as_uint(x), b = a;
  pl32sw(a, b);
  return __uint_as_float(a) + __uint_as_float(b);
#else
  return x + __shfl_xor(x, 32, 64);
#endif
}

// ---------------- conversion kernels ----------------

__global__ __launch_bounds__(256) void cvt_x(const float* __restrict__ x,
                                             ushort* __restrict__ xb) {
  int i = (blockIdx.x * 256 + threadIdx.x) * 4;
  float4 v = *(const float4*)&x[i];
  ushort4 o;
  o.x = f2bf(v.x); o.y = f2bf(v.y); o.z = f2bf(v.z); o.w = f2bf(v.w);
  *(ushort4*)&xb[i] = o;
}

// W [K][N] fp32 -> WT [N][K] bf16, 64x64 tiles, vectorized
__global__ __launch_bounds__(256) void cvt_wt(const float* __restrict__ W0,
                                              const float* __restrict__ W1,
                                              const float* __restrict__ W2,
                                              const float* __restrict__ W3,
                                              ushort* __restrict__ out) {
  const float* W = blockIdx.z == 0 ? W0 : blockIdx.z == 1 ? W1
                   : blockIdx.z == 2 ? W2 : W3;
  ushort* WT = out + (size_t)blockIdx.z * DMODEL * DMODEL;
  __shared__ float tile[64][65];
  const int n0 = blockIdx.x * 64, k0 = blockIdx.y * 64;
#pragma unroll
  for (int i = 0; i < 4; ++i) {
    int chunk = i * 256 + threadIdx.x;  // 0..1023
    int r = chunk >> 4, c4 = chunk & 15;
    float4 v = *(const float4*)&W[(size_t)(k0 + r) * DMODEL + n0 + c4 * 4];
    tile[r][c4 * 4 + 0] = v.x; tile[r][c4 * 4 + 1] = v.y;
    tile[r][c4 * 4 + 2] = v.z; tile[r][c4 * 4 + 3] = v.w;
  }
  __syncthreads();
#pragma unroll
  for (int i = 0; i < 4; ++i) {
    int chunk = i * 256 + threadIdx.x;
    int r = chunk >> 4, c4 = chunk & 15;
    ushort4 o;
    o.x = f2bf(tile[c4 * 4 + 0][r]); o.y = f2bf(tile[c4 * 4 + 1][r]);
    o.z = f2bf(tile[c4 * 4 + 2][r]); o.w = f2bf(tile[c4 * 4 + 3][r]);
    *(ushort4*)&WT[(size_t)(n0 + r) * DMODEL + k0 + c4 * 4] = o;
  }
}

// V [B,H,S,HD] -> Vt [B,H,HD,S], 32x32 LDS tiles
__global__ __launch_bounds__(256) void trV(const ushort* __restrict__ V,
                                           ushort* __restrict__ Vt) {
  const int bh = blockIdx.z;
  const ushort* src = V + (size_t)bh * S_LEN * HDIM;
  ushort* dst = Vt + (size_t)bh * HDIM * S_LEN;
  __shared__ ushort tile[32][33];
  int s0 = blockIdx.x * 32, h0 = blockIdx.y * 32;
  int tx = threadIdx.x & 31, ty = threadIdx.x >> 5;  // 32 x 8
#pragma unroll
  for (int i = 0; i < 32; i += 8)
    tile[ty + i][tx] = src[(size_t)(s0 + ty + i) * HDIM + h0 + tx];
  __syncthreads();
#pragma unroll
  for (int i = 0; i < 32; i += 8)
    dst[(size_t)(h0 + ty + i) * S_LEN + s0 + tx] = tile[tx][ty + i];
}

// ---------------- QKV GEMM: 256x192 tile, 8 waves, phase-paced ------------
__global__ __launch_bounds__(512) void gemm256(
    const ushort* __restrict__ A, const ushort* __restrict__ Bt,
    const float* __restrict__ b0, const float* __restrict__ b1,
    const float* __restrict__ b2, ushort* __restrict__ outQ,
    ushort* __restrict__ outK, ushort* __restrict__ outV) {
  const int flat = blockIdx.y * 16 + blockIdx.x;       // 0..255
  const int swz = (flat & 7) * 32 + (flat >> 3);       // bijective (256=8*32)
  const int bx = swz & 15, by = swz >> 4;
  const int m0 = bx * 256, n0 = by * 192;

  __shared__ __align__(16) ushort Al[2][256 * 64];  // 64 KB
  __shared__ __align__(16) ushort Bl[2][192 * 64];  // 48 KB

  const int tid = threadIdx.x;
  const int lane = tid & 63, wid = tid >> 6;
  const int wr = wid >> 2, wc = wid & 3;
  const int fr = lane & 15, hi16 = lane >> 4;

  f32x4 acc[8][3] = {};

#pragma unroll
  for (int l = 0; l < 4; ++l) {
    int chunk = l * 512 + tid;
    int row = chunk >> 3, cpos = chunk & 7;
    int scol = (cpos ^ (row & 7)) * 8;
    gload_lds16(&A[(size_t)(m0 + row) * DMODEL + scol], &Al[0][chunk * 8]);
  }
#pragma unroll
  for (int l = 0; l < 3; ++l) {
    int chunk = l * 512 + tid;
    int row = chunk >> 3, cpos = chunk & 7;
    int scol = (cpos ^ (row & 7)) * 8;
    gload_lds16(&Bt[(size_t)(n0 + row) * DMODEL + scol], &Bl[0][chunk * 8]);
  }
  __syncthreads();

  for (int t = 0; t < 16; ++t) {
    const int bt = t & 1;
    bf16x8 bfr[3];
#pragma unroll
    for (int s = 0; s < 4; ++s) {
      const int kk = s >> 1, mh = s & 1;
      bf16x8 af[4];
#pragma unroll
      for (int q = 0; q < 4; ++q) {
        int rl = wr * 128 + (mh * 4 + q) * 16 + fr;
        af[q] = *(const bf16x8*)&Al[bt][rl * 64 +
                                        ((kk * 4 + hi16) ^ (rl & 7)) * 8];
      }
      if (mh == 0) {
#pragma unroll
        for (int nf = 0; nf < 3; ++nf) {
          int rl = wc * 48 + nf * 16 + fr;
          bfr[nf] = *(const bf16x8*)&Bl[bt][rl * 64 +
                                            ((kk * 4 + hi16) ^ (rl & 7)) * 8];
        }
      }
      if (t + 1 < 16 && s < 2) {
        const int k64 = (t + 1) * 64;
        if (s == 0) {
#pragma unroll
          for (int l = 0; l < 4; ++l) {
            int chunk = l * 512 + tid;
            int row = chunk >> 3, cpos = chunk & 7;
            int scol = (cpos ^ (row & 7)) * 8;
            gload_lds16(&A[(size_t)(m0 + row) * DMODEL + k64 + scol],
                        &Al[bt ^ 1][chunk * 8]);
          }
        } else {
#pragma unroll
          for (int l = 0; l < 3; ++l) {
            int chunk = l * 512 + tid;
            int row = chunk >> 3, cpos = chunk & 7;
            int scol = (cpos ^ (row & 7)) * 8;
            gload_lds16(&Bt[(size_t)(n0 + row) * DMODEL + k64 + scol],
                        &Bl[bt ^ 1][chunk * 8]);
          }
        }
      }
      __builtin_amdgcn_s_barrier();
      __builtin_amdgcn_s_setprio(1);
#pragma unroll
      for (int q = 0; q < 4; ++q)
#pragma unroll
        for (int nf = 0; nf < 3; ++nf)
          acc[mh * 4 + q][nf] = __builtin_amdgcn_mfma_f32_16x16x32_bf16(
              af[q], bfr[nf], acc[mh * 4 + q][nf], 0, 0, 0);
      __builtin_amdgcn_s_setprio(0);
      if (s < 3) __builtin_amdgcn_s_barrier();
    }
    __syncthreads();
  }

#pragma unroll
  for (int mf = 0; mf < 8; ++mf) {
#pragma unroll
    for (int nf = 0; nf < 3; ++nf) {
      int col = n0 + wc * 48 + nf * 16 + fr;
      int z = col >> 10, cw = col & 1023;
      float bval = z == 0 ? b0[cw] : z == 1 ? b1[cw] : b2[cw];
      int h = cw >> 6, hd = cw & (HDIM - 1);
      ushort* dst = (z == 0) ? outQ : (z == 1) ? outK : outV;
#pragma unroll
      for (int rg = 0; rg < 4; ++rg) {
        int row = m0 + wr * 128 + mf * 16 + hi16 * 4 + rg;
        int b = row >> 11, sq = row & (S_LEN - 1);
        float val = acc[mf][nf][rg] + bval;
        dst[(((size_t)(b * NHEAD + h)) * S_LEN + sq) * HDIM + hd] = f2bf(val);
      }
    }
  }
}

// ---------------- out-proj GEMM (128x128 tile, BK=64, 4-sub-phase paced) --
__global__ __launch_bounds__(256) void gemm128o(
    const ushort* __restrict__ A, const ushort* __restrict__ Bt,
    const float* __restrict__ b0, float* __restrict__ outB) {
  const int NT = 256;
  const int flat = blockIdx.y * 32 + blockIdx.x;
  const int swz = (flat & 7) * (NT >> 3) + (flat >> 3);
  const int bx = swz & 31, by = swz >> 5;
  const int m0 = bx * 128, n0 = by * 128;

  __shared__ __align__(16) ushort Alds[2][128 * 64];
  __shared__ __align__(16) ushort Blds[2][128 * 64];

  const int tid = threadIdx.x;
  const int lane = tid & 63, w = tid >> 6;
  const int wr = w >> 1, wc = w & 1;
  const int fr = lane & 15, hi16 = lane >> 4;

  f32x4 acc[4][4] = {};

  // prologue: stage K-tile 0 (A and B) into buf 0
#pragma unroll
  for (int it = 0; it < 4; ++it) {
    int c = it * 256 + tid;
    int row = c >> 3;
    int sc = ((c & 7) ^ (row & 7)) * 8;
    gload_lds16(&A[(size_t)(m0 + row) * DMODEL + sc], &Alds[0][c * 8]);
    gload_lds16(&Bt[(size_t)(n0 + row) * DMODEL + sc], &Blds[0][c * 8]);
  }
  __syncthreads();

  for (int t = 0; t < 16; ++t) {
    const int bt = t & 1;
#pragma unroll
    for (int s = 0; s < 2; ++s) {  // kk sub-phases
      bf16x8 af[4], bfr[4];
#pragma unroll
      for (int i = 0; i < 4; ++i) {
        int row = wr * 64 + i * 16 + fr;
        af[i] = *(const bf16x8*)&Alds[bt][row * 64 +
                                          ((s * 4 + hi16) ^ (row & 7)) * 8];
      }
#pragma unroll
      for (int j = 0; j < 4; ++j) {
        int row = wc * 64 + j * 16 + fr;
        bfr[j] = *(const bf16x8*)&Blds[bt][row * 64 +
                                           ((s * 4 + hi16) ^ (row & 7)) * 8];
      }
      // stage K-tile t+1 early: A at s=0, B at s=1
      if (t + 1 < 16) {
        const int k64 = (t + 1) * 64;
#pragma unroll
        for (int it = 0; it < 4; ++it) {
          int c = it * 256 + tid;
          int row = c >> 3;
          int sc = ((c & 7) ^ (row & 7)) * 8;
          if (s == 0)
            gload_lds16(&A[(size_t)(m0 + row) * DMODEL + k64 + sc],
                        &Alds[bt ^ 1][c * 8]);
          else
            gload_lds16(&Bt[(size_t)(n0 + row) * DMODEL + k64 + sc],
                        &Blds[bt ^ 1][c * 8]);
        }
      }
      __builtin_amdgcn_s_barrier();  // pacing
      __builtin_amdgcn_s_setprio(1);
#pragma unroll
      for (int i = 0; i < 4; ++i)
#pragma unroll
        for (int j = 0; j < 4; ++j)
          acc[i][j] = __builtin_amdgcn_mfma_f32_16x16x32_bf16(af[i], bfr[j],
                                                              acc[i][j], 0, 0, 0);
      __builtin_amdgcn_s_setprio(0);
      if (s < 1) __builtin_amdgcn_s_barrier();
    }
    __syncthreads();  // tile reads done + stage drained
  }

#pragma unroll
  for (int i = 0; i < 4; ++i) {
#pragma unroll
    for (int j = 0; j < 4; ++j) {
      int col = n0 + wc * 64 + j * 16 + fr;
      float bval = b0[col];
#pragma unroll
      for (int r = 0; r < 4; ++r) {
        int row = m0 + wr * 64 + i * 16 + hi16 * 4 + r;
        outB[(size_t)row * DMODEL + col] = acc[i][j][r] + bval;
      }
    }
  }
}

// ---------------- flash attention (causal), split-KV 4-wave ----------------
// Round-17 ILP edits: QK chains interleaved; PV accumulator split A/B.
__global__ __launch_bounds__(256, 2) void attn4(const ushort* __restrict__ Q,
                                                const ushort* __restrict__ K,
                                                const ushort* __restrict__ Vt,
                                                ushort* __restrict__ ctx) {
  const int n = blockIdx.x;
  const int v = (n & 7) * 64 + (n >> 3);  // bijective XCD-contiguous (512=8*64)
  const int ptile = v & 15, bh = v >> 4;
  const int b = bh >> 4, h = bh & 15;
  const int tid = threadIdx.x;
  const int lane = tid & 63, wid = tid >> 6;
  const int p = wid >> 1;        // KV-parity pair: 0 even steps, 1 odd
  const int wq = wid & 1;        // 32-row q-subtile within the 64-row tile
  const int q32 = lane & 31, hi = lane >> 5;
  const bool lo_half = (hi == 0);
  const int tid2 = tid & 127;    // pair-local thread id (2 waves = 128 thr)

  const ushort* Qb = Q + (size_t)bh * S_LEN * HDIM;
  const ushort* Kb = K + (size_t)bh * S_LEN * HDIM;
  const ushort* Vb = Vt + (size_t)bh * HDIM * S_LEN;

  __shared__ __align__(16) ushort Kl[2][2][64 * 64];  // [pair][buf] 32 KB
  __shared__ __align__(16) ushort Vl[2][2][64 * 64];  // 32 KB
  float* scr = (float*)&Kl[0][0][0];  // merge scratch overlay (post-loop only)

  const float C = 0.125f * 1.44269504f;  // scale * log2(e)

  for (int ph = 0; ph < 2; ++ph) {
    const int j = ph ? 31 - ptile : ptile;  // 64-row q-tile index, 0..31
    const int qbase = j * 64 + wq * 32;
    const int qrow = qbase + q32;

    bf16x8 qf[4];
#pragma unroll
    for (int s = 0; s < 4; ++s)
      qf[s] = *(const bf16x8*)&Qb[(size_t)qrow * HDIM + s * 16 + hi * 8];

    f32x16 oaccA[2] = {}, oaccB[2] = {};  // PV split: A = t0, B = t1 k-slices
    float mraw = -1e30f, lsum = 0.f;
    const int NS = (j >> 1) + 1;  // iterations (pair0 steps; pair1 <= this)

    // prologue: pair p stages its first step (s0 = p) into buf 0
    if (p <= j) {
      const int kv = p * 64;
#pragma unroll
      for (int it = 0; it < 4; ++it) {
        int chunk = it * 128 + tid2;
        int row = chunk >> 3, sc = ((chunk & 7) ^ (row & 7)) * 8;
        gload_lds16(&Kb[(size_t)(kv + row) * HDIM + sc], &Kl[p][0][chunk * 8]);
        gload_lds16(&Vb[(size_t)row * S_LEN + kv + sc], &Vl[p][0][chunk * 8]);
      }
    }
    __syncthreads();

    int buf = 0;
    for (int it = 0; it < NS; ++it) {
      const int s = 2 * it + p;      // my global KV step
      const int kv0 = s * 64;

      // issue my pair's next-tile stage (s+2) first — overlaps compute
      if (s + 2 <= j) {
        const int kvn = kv0 + 128;
#pragma unroll
        for (int st = 0; st < 4; ++st) {
          int chunk = st * 128 + tid2;
          int row = chunk >> 3, sc = ((chunk & 7) ^ (row & 7)) * 8;
          gload_lds16(&Kb[(size_t)(kvn + row) * HDIM + sc],
                      &Kl[p][buf ^ 1][chunk * 8]);
          gload_lds16(&Vb[(size_t)row * S_LEN + kvn + sc],
                      &Vl[p][buf ^ 1][chunk * 8]);
        }
      }

      if (s <= j) {
        // ---- QK^T: S^T[k][q], 2 tiles of 32 k, chains INTERLEAVED ----
        // rsw identical for rows q32 and 32+q32 ((32+q32)&7 == q32&7).
        const int rsw = (q32 & 7);
        f32x16 sa[2] = {};
        __builtin_amdgcn_s_setprio(1);
#pragma unroll
        for (int sl = 0; sl < 4; ++sl) {
          bf16x8 kf0 = *(const bf16x8*)&Kl[p][buf][q32 * 64 +
                                                   ((sl * 2 + hi) ^ rsw) * 8];
          bf16x8 kf1 = *(const bf16x8*)&Kl[p][buf][(32 + q32) * 64 +
                                                   ((sl * 2 + hi) ^ rsw) * 8];
          sa[0] = __builtin_amdgcn_mfma_f32_32x32x16_bf16(kf0, qf[sl], sa[0],
                                                          0, 0, 0);
          sa[1] = __builtin_amdgcn_mfma_f32_32x32x16_bf16(kf1, qf[sl], sa[1],
                                                          0, 0, 0);
        }
        __builtin_amdgcn_s_setprio(0);

        // ---- V^T A-frags from LDS ----
        bf16x8 vf[2][4];
#pragma unroll
        for (int t2 = 0; t2 < 2; ++t2) {
          const int row = t2 * 32 + q32;
#pragma unroll
          for (int sl = 0; sl < 4; ++sl)
            vf[t2][sl] = *(const bf16x8*)&Vl[p][buf][row * 64 +
                                                     ((sl * 2 + hi) ^ rsw) * 8];
        }

        // ---- causal mask (only step s == j masks; wave-uniform) ----
        if (kv0 + 63 > qbase) {
          const int khi = kv0 + 4 * hi;
#pragma unroll
          for (int t = 0; t < 2; ++t)
#pragma unroll
            for (int rr = 0; rr < 16; ++rr) {
              int kg = khi + t * 32 + (rr & 3) + 8 * (rr >> 2);
              if (kg > qrow) sa[t][rr] = -1e30f;
            }
        }

        // ---- online softmax (raw domain; lane-local rows) ----
        float tmv[8];
#pragma unroll
        for (int rr = 0; rr < 8; ++rr)
          tmv[rr] = fmaxf(fmaxf(sa[0][rr], sa[0][rr + 8]),
                          fmaxf(sa[1][rr], sa[1][rr + 8]));
        float t0 = fmaxf(fmaxf(tmv[0], tmv[1]), fmaxf(tmv[2], tmv[3]));
        float t1 = fmaxf(fmaxf(tmv[4], tmv[5]), fmaxf(tmv[6], tmv[7]));
        float tm = halfcomb_max(fmaxf(t0, t1));

        if (!__all(tm <= mraw + 64.f)) {  // T13 defer-max
          float mnew = fmaxf(mraw, tm);
          float alpha = __builtin_exp2f((mraw - mnew) * C);
          lsum *= alpha;
#pragma unroll
          for (int rr = 0; rr < 16; ++rr) {
            oaccA[0][rr] *= alpha; oaccA[1][rr] *= alpha;
            oaccB[0][rr] *= alpha; oaccB[1][rr] *= alpha;
          }
          mraw = mnew;
        }
        const float mC = mraw * C;
        float psum = 0.f;
#pragma unroll
        for (int t = 0; t < 2; ++t)
#pragma unroll
          for (int rr = 0; rr < 16; ++rr) {
            float pp = __builtin_exp2f(__builtin_fmaf(sa[t][rr], C, -mC));
            sa[t][rr] = pp;
            psum += pp;
          }
        lsum += halfcomb_sum(psum);

        // ---- P^T -> bf16 B-frags + PV (A/B split: t0 -> A, t1 -> B) ----
        __builtin_amdgcn_s_setprio(1);
#pragma unroll
        for (int t = 0; t < 2; ++t) {
#pragma unroll
          for (int half = 0; half < 2; ++half) {
            const int rb = half * 8;
            unsigned a0 = pack2bf(sa[t][rb + 0], sa[t][rb + 1]);
            unsigned a1 = pack2bf(sa[t][rb + 2], sa[t][rb + 3]);
            unsigned b0w = pack2bf(sa[t][rb + 4], sa[t][rb + 5]);
            unsigned b1w = pack2bf(sa[t][rb + 6], sa[t][rb + 7]);
            union { unsigned u[4]; bf16x8 v; } pf;
#ifdef HAVE_PL32
            pl32sw(a0, b0w);
            pl32sw(a1, b1w);
            pf.u[0] = a0; pf.u[1] = a1; pf.u[2] = b0w; pf.u[3] = b1w;
#else
            unsigned xa0 = __shfl_xor(a0, 32, 64);
            unsigned xa1 = __shfl_xor(a1, 32, 64);
            unsigned xb0 = __shfl_xor(b0w, 32, 64);
            unsigned xb1 = __shfl_xor(b1w, 32, 64);
            pf.u[0] = lo_half ? a0 : xb0;
            pf.u[1] = lo_half ? a1 : xb1;
            pf.u[2] = lo_half ? xa0 : b0w;
            pf.u[3] = lo_half ? xa1 : b1w;
#endif
            if (t == 0) {
              oaccA[0] = __builtin_amdgcn_mfma_f32_32x32x16_bf16(
                  vf[0][half], pf.v, oaccA[0], 0, 0, 0);
              oaccA[1] = __builtin_amdgcn_mfma_f32_32x32x16_bf16(
                  vf[1][half], pf.v, oaccA[1], 0, 0, 0);
            } else {
              oaccB[0] = __builtin_amdgcn_mfma_f32_32x32x16_bf16(
                  vf[0][2 + half], pf.v, oaccB[0], 0, 0, 0);
              oaccB[1] = __builtin_amdgcn_mfma_f32_32x32x16_bf16(
                  vf[1][2 + half], pf.v, oaccB[1], 0, 0, 0);
            }
          }
        }
        __builtin_amdgcn_s_setprio(0);
      }

      __syncthreads();  // stage complete + LDS reads done before overwrite
      buf ^= 1;
    }

    // combine the PV split before publish/merge
#pragma unroll
    for (int tt = 0; tt < 2; ++tt)
#pragma unroll
      for (int rr = 0; rr < 16; ++rr) oaccA[tt][rr] += oaccB[tt][rr];

    // ---- merge pair partials: pair1 publishes, pair0 merges + stores ----
    const int base = (wq * 64 + lane) * 37;  // stride-37: conflict-free
    if (p == 1) {
      scr[base + 0] = mraw;
      scr[base + 1] = lsum;
#pragma unroll
      for (int t = 0; t < 2; ++t)
#pragma unroll
        for (int rr = 0; rr < 16; ++rr)
          scr[base + 2 + t * 16 + rr] = oaccA[t][rr];
    }
    __syncthreads();
    if (p == 0) {
      const float mB = scr[base + 0], lB = scr[base + 1];
      const float mS = fmaxf(mraw, mB);
      const float aA = __builtin_exp2f((mraw - mS) * C);
      const float aB = __builtin_exp2f((mB - mS) * C);
      const float lT = lsum * aA + lB * aB;
      const float linv = 1.0f / lT;
      ushort* crow = &ctx[((size_t)(b * S_LEN) + qrow) * DMODEL + h * HDIM];
#pragma unroll
      for (int t = 0; t < 2; ++t)
#pragma unroll
        for (int g2 = 0; g2 < 4; ++g2) {
          ushort4 o;  // hd = t*32 + g2*8 + hi*4 + r
          float m0 = oaccA[t][g2 * 4 + 0] * aA + scr[base + 2 + t * 16 + g2 * 4 + 0] * aB;
          float m1 = oaccA[t][g2 * 4 + 1] * aA + scr[base + 2 + t * 16 + g2 * 4 + 1] * aB;
          float m2 = oaccA[t][g2 * 4 + 2] * aA + scr[base + 2 + t * 16 + g2 * 4 + 2] * aB;
          float m3 = oaccA[t][g2 * 4 + 3] * aA + scr[base + 2 + t * 16 + g2 * 4 + 3] * aB;
          o.x = f2bf(m0 * linv); o.y = f2bf(m1 * linv);
          o.z = f2bf(m2 * linv); o.w = f2bf(m3 * linv);
          *(ushort4*)&crow[t * 32 + g2 * 8 + hi * 4] = o;
        }
    }
    __syncthreads();  // scratch reads done before next phase restages LDS
  }
}

// ---------------- launch ----------------

extern "C" void kernel_launch(void* const* d_in, const int* in_sizes, int n_in,
                              void* d_out, int out_size, void* d_ws,
                              size_t ws_size, hipStream_t stream) {
  const float* x  = (const float*)d_in[0];
  const float* Wq = (const float*)d_in[1];
  const float* bq = (const float*)d_in[2];
  const float* Wk = (const float*)d_in[3];
  const float* bk = (const float*)d_in[4];
  const float* Wv = (const float*)d_in[5];
  const float* bv = (const float*)d_in[6];
  const float* Wo = (const float*)d_in[7];
  const float* bo = (const float*)d_in[8];

  char* ws = (char*)d_ws;
  ushort* Xbf = (ushort*)ws;                               // 8 MB
  ushort* WT  = (ushort*)(ws + (size_t)8 * 1024 * 1024);   // 8 MB
  ushort* QKV = (ushort*)(ws + (size_t)16 * 1024 * 1024);  // Q,K then Vt
  ushort* CTX = (ushort*)(ws + (size_t)40 * 1024 * 1024);  // V-rowmajor, ctx

  const size_t QKV_ELEMS = (size_t)MROWS * DMODEL;  // 4 M elems = 8 MB
  const size_t W_ELEMS = (size_t)DMODEL * DMODEL;

  ushort* Qp  = QKV;                  // [B,H,S,HD]
  ushort* Kp  = QKV + QKV_ELEMS;      // [B,H,S,HD]
  ushort* Vtp = QKV + 2 * QKV_ELEMS;  // [B,H,HD,S]  (trV output)
  ushort* Vrp = CTX;                  // [B,H,S,HD]  (gemm256 scratch out)

  cvt_x<<<4096, 256, 0, stream>>>(x, Xbf);
  cvt_wt<<<dim3(16, 16, 4), 256, 0, stream>>>(Wq, Wk, Wv, Wo, WT);
  gemm256<<<dim3(16, 16), 512, 0, stream>>>(Xbf, WT, bq, bk, bv, Qp, Kp, Vrp);
  trV<<<dim3(64, 2, 32), 256, 0, stream>>>(Vrp, Vtp);
  attn4<<<dim3(512), 256, 0, stream>>>(Qp, Kp, Vtp, CTX);
  gemm128o<<<dim3(32, 8), 256, 0, stream>>>(CTX, WT + 3 * W_ELEMS, bo,
                                            (float*)d_out);
}

// Round 19
// 118.248 us; speedup vs baseline: 1.3995x; 1.0131x over previous
//
#include <hip/hip_runtime.h>

// MHA: B=2, S=2048, D=1024, H=16, HD=64, causal, scale=1/8.
// Round 19: fix attn8 NaN — guard fully-masked KV steps (kv0 > qbase+31):
// skipped compute (wave-uniform; barriers still executed). Root cause: at
// fully-masked steps mraw=-1e30=sa, and exp2(fma(sa,C,-mraw*C)) sees fma
// rounding noise ~1e22 -> Inf -> Inf*0=NaN at merge. Guard also restores
// the "every computed lane has >=1 valid entry" invariant (kv0,qbase both
// multiples of 32). Everything else identical to round 18.
//   ws layout (bytes):
//     [0,8M)    Xbf  : x as bf16 [4096,1024]
//     [8M,16M)  WT   : WqT,WkT,WvT,WoT bf16 [1024,1024] each ([N][K])
//     [16M,32M) Q,K  : [B,H,S,HD] bf16
//     [32M,40M) Vt   : [B,H,HD,S] bf16 (written by trV)
//     [40M,48M) CTX  : first V row-major (gemm256 out), then ctx [B,S,D]

#define S_LEN 2048
#define DMODEL 1024
#define NHEAD 16
#define HDIM 64
#define MROWS 4096  // B*S

typedef __bf16 bf16x8 __attribute__((ext_vector_type(8)));
typedef float f32x4 __attribute__((ext_vector_type(4)));
typedef float f32x16 __attribute__((ext_vector_type(16)));

__device__ __forceinline__ ushort f2bf(float f) {
  union { float f; unsigned u; } v; v.f = f;
  unsigned r = v.u + 0x7fffu + ((v.u >> 16) & 1u);  // RNE
  return (ushort)(r >> 16);
}

__device__ __forceinline__ void gload_lds16(const ushort* g, ushort* l) {
  __builtin_amdgcn_global_load_lds(
      (const __attribute__((address_space(1))) void*)g,
      (__attribute__((address_space(3))) void*)l, 16, 0, 0);
}

// pack two f32 -> one dword of 2 bf16 (compiler emits v_cvt_pk_bf16_f32)
__device__ __forceinline__ unsigned pack2bf(float lo, float hi) {
  union { __bf16 h[2]; unsigned u; } t;
  t.h[0] = (__bf16)lo; t.h[1] = (__bf16)hi;
  return t.u;
}

#if __has_builtin(__builtin_amdgcn_permlane32_swap)
#define HAVE_PL32 1
// after call: a = {a.lo | b.lo}, b = {a.hi | b.hi}  (lane<32 | lane>=32)
__device__ __forceinline__ void pl32sw(unsigned& a, unsigned& b) {
  auto r = __builtin_amdgcn_permlane32_swap((int)a, (int)b, false, false);
  a = (unsigned)r[0];
  b = (unsigned)r[1];
}
#endif

__device__ __forceinline__ float halfcomb_max(float x) {
#ifdef HAVE_PL32
  unsigned a = __float_as_uint(x), b = a;
  pl32sw(a, b);
  return fmaxf(__uint_as_float(a), __uint_as_float(b));
#else
  return fmaxf(x, __shfl_xor(x, 32, 64));
#endif
}
__device__ __forceinline__ float halfcomb_sum(float x) {
#ifdef HAVE_PL32
  unsigned a = __float_as_uint(x), b = a;
  pl32sw(a, b);
  return __uint_as_float(a) + __uint_as_float(b);
#else
  return x + __shfl_xor(x, 32, 64);
#endif
}

// ---------------- conversion kernels ----------------

__global__ __launch_bounds__(256) void cvt_x(const float* __restrict__ x,
                                             ushort* __restrict__ xb) {
  int i = (blockIdx.x * 256 + threadIdx.x) * 4;
  float4 v = *(const float4*)&x[i];
  ushort4 o;
  o.x = f2bf(v.x); o.y = f2bf(v.y); o.z = f2bf(v.z); o.w = f2bf(v.w);
  *(ushort4*)&xb[i] = o;
}

// W [K][N] fp32 -> WT [N][K] bf16, 64x64 tiles, vectorized
__global__ __launch_bounds__(256) void cvt_wt(const float* __restrict__ W0,
                                              const float* __restrict__ W1,
                                              const float* __restrict__ W2,
                                              const float* __restrict__ W3,
                                              ushort* __restrict__ out) {
  const float* W = blockIdx.z == 0 ? W0 : blockIdx.z == 1 ? W1
                   : blockIdx.z == 2 ? W2 : W3;
  ushort* WT = out + (size_t)blockIdx.z * DMODEL * DMODEL;
  __shared__ float tile[64][65];
  const int n0 = blockIdx.x * 64, k0 = blockIdx.y * 64;
#pragma unroll
  for (int i = 0; i < 4; ++i) {
    int chunk = i * 256 + threadIdx.x;  // 0..1023
    int r = chunk >> 4, c4 = chunk & 15;
    float4 v = *(const float4*)&W[(size_t)(k0 + r) * DMODEL + n0 + c4 * 4];
    tile[r][c4 * 4 + 0] = v.x; tile[r][c4 * 4 + 1] = v.y;
    tile[r][c4 * 4 + 2] = v.z; tile[r][c4 * 4 + 3] = v.w;
  }
  __syncthreads();
#pragma unroll
  for (int i = 0; i < 4; ++i) {
    int chunk = i * 256 + threadIdx.x;
    int r = chunk >> 4, c4 = chunk & 15;
    ushort4 o;
    o.x = f2bf(tile[c4 * 4 + 0][r]); o.y = f2bf(tile[c4 * 4 + 1][r]);
    o.z = f2bf(tile[c4 * 4 + 2][r]); o.w = f2bf(tile[c4 * 4 + 3][r]);
    *(ushort4*)&WT[(size_t)(n0 + r) * DMODEL + k0 + c4 * 4] = o;
  }
}

// V [B,H,S,HD] -> Vt [B,H,HD,S], 32x32 LDS tiles
__global__ __launch_bounds__(256) void trV(const ushort* __restrict__ V,
                                           ushort* __restrict__ Vt) {
  const int bh = blockIdx.z;
  const ushort* src = V + (size_t)bh * S_LEN * HDIM;
  ushort* dst = Vt + (size_t)bh * HDIM * S_LEN;
  __shared__ ushort tile[32][33];
  int s0 = blockIdx.x * 32, h0 = blockIdx.y * 32;
  int tx = threadIdx.x & 31, ty = threadIdx.x >> 5;  // 32 x 8
#pragma unroll
  for (int i = 0; i < 32; i += 8)
    tile[ty + i][tx] = src[(size_t)(s0 + ty + i) * HDIM + h0 + tx];
  __syncthreads();
#pragma unroll
  for (int i = 0; i < 32; i += 8)
    dst[(size_t)(h0 + ty + i) * S_LEN + s0 + tx] = tile[tx][ty + i];
}

// ---------------- QKV GEMM: 256x192 tile, 8 waves, phase-paced ------------
__global__ __launch_bounds__(512) void gemm256(
    const ushort* __restrict__ A, const ushort* __restrict__ Bt,
    const float* __restrict__ b0, const float* __restrict__ b1,
    const float* __restrict__ b2, ushort* __restrict__ outQ,
    ushort* __restrict__ outK, ushort* __restrict__ outV) {
  const int flat = blockIdx.y * 16 + blockIdx.x;       // 0..255
  const int swz = (flat & 7) * 32 + (flat >> 3);       // bijective (256=8*32)
  const int bx = swz & 15, by = swz >> 4;
  const int m0 = bx * 256, n0 = by * 192;

  __shared__ __align__(16) ushort Al[2][256 * 64];  // 64 KB
  __shared__ __align__(16) ushort Bl[2][192 * 64];  // 48 KB

  const int tid = threadIdx.x;
  const int lane = tid & 63, wid = tid >> 6;
  const int wr = wid >> 2, wc = wid & 3;
  const int fr = lane & 15, hi16 = lane >> 4;

  f32x4 acc[8][3] = {};

#pragma unroll
  for (int l = 0; l < 4; ++l) {
    int chunk = l * 512 + tid;
    int row = chunk >> 3, cpos = chunk & 7;
    int scol = (cpos ^ (row & 7)) * 8;
    gload_lds16(&A[(size_t)(m0 + row) * DMODEL + scol], &Al[0][chunk * 8]);
  }
#pragma unroll
  for (int l = 0; l < 3; ++l) {
    int chunk = l * 512 + tid;
    int row = chunk >> 3, cpos = chunk & 7;
    int scol = (cpos ^ (row & 7)) * 8;
    gload_lds16(&Bt[(size_t)(n0 + row) * DMODEL + scol], &Bl[0][chunk * 8]);
  }
  __syncthreads();

  for (int t = 0; t < 16; ++t) {
    const int bt = t & 1;
    bf16x8 bfr[3];
#pragma unroll
    for (int s = 0; s < 4; ++s) {
      const int kk = s >> 1, mh = s & 1;
      bf16x8 af[4];
#pragma unroll
      for (int q = 0; q < 4; ++q) {
        int rl = wr * 128 + (mh * 4 + q) * 16 + fr;
        af[q] = *(const bf16x8*)&Al[bt][rl * 64 +
                                        ((kk * 4 + hi16) ^ (rl & 7)) * 8];
      }
      if (mh == 0) {
#pragma unroll
        for (int nf = 0; nf < 3; ++nf) {
          int rl = wc * 48 + nf * 16 + fr;
          bfr[nf] = *(const bf16x8*)&Bl[bt][rl * 64 +
                                            ((kk * 4 + hi16) ^ (rl & 7)) * 8];
        }
      }
      if (t + 1 < 16 && s < 2) {
        const int k64 = (t + 1) * 64;
        if (s == 0) {
#pragma unroll
          for (int l = 0; l < 4; ++l) {
            int chunk = l * 512 + tid;
            int row = chunk >> 3, cpos = chunk & 7;
            int scol = (cpos ^ (row & 7)) * 8;
            gload_lds16(&A[(size_t)(m0 + row) * DMODEL + k64 + scol],
                        &Al[bt ^ 1][chunk * 8]);
          }
        } else {
#pragma unroll
          for (int l = 0; l < 3; ++l) {
            int chunk = l * 512 + tid;
            int row = chunk >> 3, cpos = chunk & 7;
            int scol = (cpos ^ (row & 7)) * 8;
            gload_lds16(&Bt[(size_t)(n0 + row) * DMODEL + k64 + scol],
                        &Bl[bt ^ 1][chunk * 8]);
          }
        }
      }
      __builtin_amdgcn_s_barrier();
      __builtin_amdgcn_s_setprio(1);
#pragma unroll
      for (int q = 0; q < 4; ++q)
#pragma unroll
        for (int nf = 0; nf < 3; ++nf)
          acc[mh * 4 + q][nf] = __builtin_amdgcn_mfma_f32_16x16x32_bf16(
              af[q], bfr[nf], acc[mh * 4 + q][nf], 0, 0, 0);
      __builtin_amdgcn_s_setprio(0);
      if (s < 3) __builtin_amdgcn_s_barrier();
    }
    __syncthreads();
  }

#pragma unroll
  for (int mf = 0; mf < 8; ++mf) {
#pragma unroll
    for (int nf = 0; nf < 3; ++nf) {
      int col = n0 + wc * 48 + nf * 16 + fr;
      int z = col >> 10, cw = col & 1023;
      float bval = z == 0 ? b0[cw] : z == 1 ? b1[cw] : b2[cw];
      int h = cw >> 6, hd = cw & (HDIM - 1);
      ushort* dst = (z == 0) ? outQ : (z == 1) ? outK : outV;
#pragma unroll
      for (int rg = 0; rg < 4; ++rg) {
        int row = m0 + wr * 128 + mf * 16 + hi16 * 4 + rg;
        int b = row >> 11, sq = row & (S_LEN - 1);
        float val = acc[mf][nf][rg] + bval;
        dst[(((size_t)(b * NHEAD + h)) * S_LEN + sq) * HDIM + hd] = f2bf(val);
      }
    }
  }
}

// ---------------- out-proj GEMM (128x128 tile, BK=64, 4-sub-phase paced) --
__global__ __launch_bounds__(256) void gemm128o(
    const ushort* __restrict__ A, const ushort* __restrict__ Bt,
    const float* __restrict__ b0, float* __restrict__ outB) {
  const int NT = 256;
  const int flat = blockIdx.y * 32 + blockIdx.x;
  const int swz = (flat & 7) * (NT >> 3) + (flat >> 3);
  const int bx = swz & 31, by = swz >> 5;
  const int m0 = bx * 128, n0 = by * 128;

  __shared__ __align__(16) ushort Alds[2][128 * 64];
  __shared__ __align__(16) ushort Blds[2][128 * 64];

  const int tid = threadIdx.x;
  const int lane = tid & 63, w = tid >> 6;
  const int wr = w >> 1, wc = w & 1;
  const int fr = lane & 15, hi16 = lane >> 4;

  f32x4 acc[4][4] = {};

#pragma unroll
  for (int it = 0; it < 4; ++it) {
    int c = it * 256 + tid;
    int row = c >> 3;
    int sc = ((c & 7) ^ (row & 7)) * 8;
    gload_lds16(&A[(size_t)(m0 + row) * DMODEL + sc], &Alds[0][c * 8]);
    gload_lds16(&Bt[(size_t)(n0 + row) * DMODEL + sc], &Blds[0][c * 8]);
  }
  __syncthreads();

  for (int t = 0; t < 16; ++t) {
    const int bt = t & 1;
#pragma unroll
    for (int s = 0; s < 2; ++s) {  // kk sub-phases
      bf16x8 af[4], bfr[4];
#pragma unroll
      for (int i = 0; i < 4; ++i) {
        int row = wr * 64 + i * 16 + fr;
        af[i] = *(const bf16x8*)&Alds[bt][row * 64 +
                                          ((s * 4 + hi16) ^ (row & 7)) * 8];
      }
#pragma unroll
      for (int j = 0; j < 4; ++j) {
        int row = wc * 64 + j * 16 + fr;
        bfr[j] = *(const bf16x8*)&Blds[bt][row * 64 +
                                           ((s * 4 + hi16) ^ (row & 7)) * 8];
      }
      if (t + 1 < 16) {
        const int k64 = (t + 1) * 64;
#pragma unroll
        for (int it = 0; it < 4; ++it) {
          int c = it * 256 + tid;
          int row = c >> 3;
          int sc = ((c & 7) ^ (row & 7)) * 8;
          if (s == 0)
            gload_lds16(&A[(size_t)(m0 + row) * DMODEL + k64 + sc],
                        &Alds[bt ^ 1][c * 8]);
          else
            gload_lds16(&Bt[(size_t)(n0 + row) * DMODEL + k64 + sc],
                        &Blds[bt ^ 1][c * 8]);
        }
      }
      __builtin_amdgcn_s_barrier();  // pacing
      __builtin_amdgcn_s_setprio(1);
#pragma unroll
      for (int i = 0; i < 4; ++i)
#pragma unroll
        for (int j = 0; j < 4; ++j)
          acc[i][j] = __builtin_amdgcn_mfma_f32_16x16x32_bf16(af[i], bfr[j],
                                                              acc[i][j], 0, 0, 0);
      __builtin_amdgcn_s_setprio(0);
      if (s < 1) __builtin_amdgcn_s_barrier();
    }
    __syncthreads();  // tile reads done + stage drained
  }

#pragma unroll
  for (int i = 0; i < 4; ++i) {
#pragma unroll
    for (int j = 0; j < 4; ++j) {
      int col = n0 + wc * 64 + j * 16 + fr;
      float bval = b0[col];
#pragma unroll
      for (int r = 0; r < 4; ++r) {
        int row = m0 + wr * 64 + i * 16 + hi16 * 4 + r;
        outB[(size_t)row * DMODEL + col] = acc[i][j][r] + bval;
      }
    }
  }
}

// ---------------- flash attention (causal), 8-wave shared KV stream -------
// 256 blocks x 512 thr. Block: 128-row q-tile T (paired T / 15-T across
// phases). Waves: p = wid>>2 (KV parity), wq = wid&3 (32-row q-subtile).
// Each parity's 4 waves SHARE one staged K/V 64x64 tile. Fully-masked steps
// (kv0 > qbase+31) skip compute (wave-uniform; barriers still run).
__global__ __launch_bounds__(512, 1) void attn8(const ushort* __restrict__ Q,
                                                const ushort* __restrict__ K,
                                                const ushort* __restrict__ Vt,
                                                ushort* __restrict__ ctx) {
  const int blk = blockIdx.x;
  const int w2 = (blk & 7) * 32 + (blk >> 3);  // chunked XCD (256=8*32)
  const int bh = w2 >> 3, ptile = w2 & 7;      // 4 heads per XCD
  const int b = bh >> 4, h = bh & 15;
  const int tid = threadIdx.x;
  const int lane = tid & 63, wid = tid >> 6;
  const int p = wid >> 2;        // KV parity: 0 even steps, 1 odd
  const int wq = wid & 3;        // 32-row q-subtile in the 128-row tile
  const int q32 = lane & 31, hi = lane >> 5;
  const bool lo_half = (hi == 0);
  const int tidp = tid & 255;    // parity-local thread id (4 waves)

  const ushort* Qb = Q + (size_t)bh * S_LEN * HDIM;
  const ushort* Kb = K + (size_t)bh * S_LEN * HDIM;
  const ushort* Vb = Vt + (size_t)bh * HDIM * S_LEN;

  __shared__ __align__(16) ushort lds[32768];  // 64 KB
  ushort* Klp = lds;            // [ (p*2+buf)*4096 ]
  ushort* Vlp = lds + 16384;    // [ (p*2+buf)*4096 ]
  float* scr = (float*)lds;     // merge scratch (post-loop only)

  const float C = 0.125f * 1.44269504f;  // scale * log2(e)

  for (int ph = 0; ph < 2; ++ph) {
    const int T = ph ? 15 - ptile : ptile;  // 128-row q-tile index, 0..15
    const int qbase = T * 128 + wq * 32;
    const int qrow = qbase + q32;
    const int NS = T + 1;                   // steps per parity

    bf16x8 qf[4];
#pragma unroll
    for (int s = 0; s < 4; ++s)
      qf[s] = *(const bf16x8*)&Qb[(size_t)qrow * HDIM + s * 16 + hi * 8];

    f32x16 oaccA[2] = {}, oaccB[2] = {};
    float mraw = -1e30f, lsum = 0.f;

    // prologue: parity p stages its first step (s0 = p) into buf 0
    {
      const int kv = p * 64;
#pragma unroll
      for (int g = 0; g < 2; ++g) {
        int chunk = g * 256 + tidp;           // 0..511 over 64x64 tile
        int row = chunk >> 3, sc = ((chunk & 7) ^ (row & 7)) * 8;
        gload_lds16(&Kb[(size_t)(kv + row) * HDIM + sc],
                    &Klp[(p * 2 + 0) * 4096 + chunk * 8]);
        gload_lds16(&Vb[(size_t)row * S_LEN + kv + sc],
                    &Vlp[(p * 2 + 0) * 4096 + chunk * 8]);
      }
    }
    __syncthreads();

    int buf = 0;
    for (int it = 0; it < NS; ++it) {
      const int s = 2 * it + p;      // my parity's global KV step
      const int kv0 = s * 64;

      // issue next-tile stage (s+2) first — overlaps compute
      if (it + 1 < NS) {
        const int kvn = kv0 + 128;
#pragma unroll
        for (int g = 0; g < 2; ++g) {
          int chunk = g * 256 + tidp;
          int row = chunk >> 3, sc = ((chunk & 7) ^ (row & 7)) * 8;
          gload_lds16(&Kb[(size_t)(kvn + row) * HDIM + sc],
                      &Klp[(p * 2 + (buf ^ 1)) * 4096 + chunk * 8]);
          gload_lds16(&Vb[(size_t)row * S_LEN + kvn + sc],
                      &Vlp[(p * 2 + (buf ^ 1)) * 4096 + chunk * 8]);
        }
      }

      // skip fully-masked steps (wave-uniform: kv0, qbase multiples of 32,
      // so kv0 <= qbase+31 implies kv0 <= qbase => every lane has a valid k)
      if (kv0 <= qbase + 31) {
        const ushort* Kt = &Klp[(p * 2 + buf) * 4096];
        const ushort* Vtl = &Vlp[(p * 2 + buf) * 4096];
        const int rsw = (q32 & 7);

        // ---- QK^T: S^T[k][q], 2 tiles of 32 k, chains interleaved ----
        f32x16 sa[2] = {};
        __builtin_amdgcn_s_setprio(1);
#pragma unroll
        for (int sl = 0; sl < 4; ++sl) {
          bf16x8 kf0 = *(const bf16x8*)&Kt[q32 * 64 + ((sl * 2 + hi) ^ rsw) * 8];
          bf16x8 kf1 = *(const bf16x8*)&Kt[(32 + q32) * 64 +
                                           ((sl * 2 + hi) ^ rsw) * 8];
          sa[0] = __builtin_amdgcn_mfma_f32_32x32x16_bf16(kf0, qf[sl], sa[0],
                                                          0, 0, 0);
          sa[1] = __builtin_amdgcn_mfma_f32_32x32x16_bf16(kf1, qf[sl], sa[1],
                                                          0, 0, 0);
        }
        __builtin_amdgcn_s_setprio(0);

        // ---- V^T A-frags from LDS ----
        bf16x8 vf[2][4];
#pragma unroll
        for (int t2 = 0; t2 < 2; ++t2) {
          const int row = t2 * 32 + q32;
#pragma unroll
          for (int sl = 0; sl < 4; ++sl)
            vf[t2][sl] = *(const bf16x8*)&Vtl[row * 64 +
                                              ((sl * 2 + hi) ^ rsw) * 8];
        }

        // ---- causal mask (wave-uniform branch) ----
        if (kv0 + 63 > qbase) {
          const int khi = kv0 + 4 * hi;
#pragma unroll
          for (int t = 0; t < 2; ++t)
#pragma unroll
            for (int rr = 0; rr < 16; ++rr) {
              int kg = khi + t * 32 + (rr & 3) + 8 * (rr >> 2);
              if (kg > qrow) sa[t][rr] = -1e30f;
            }
        }

        // ---- online softmax (raw domain; lane-local rows) ----
        float tmv[8];
#pragma unroll
        for (int rr = 0; rr < 8; ++rr)
          tmv[rr] = fmaxf(fmaxf(sa[0][rr], sa[0][rr + 8]),
                          fmaxf(sa[1][rr], sa[1][rr + 8]));
        float t0 = fmaxf(fmaxf(tmv[0], tmv[1]), fmaxf(tmv[2], tmv[3]));
        float t1 = fmaxf(fmaxf(tmv[4], tmv[5]), fmaxf(tmv[6], tmv[7]));
        float tm = halfcomb_max(fmaxf(t0, t1));

        if (!__all(tm <= mraw + 64.f)) {  // T13 defer-max
          float mnew = fmaxf(mraw, tm);
          float alpha = __builtin_exp2f((mraw - mnew) * C);
          lsum *= alpha;
#pragma unroll
          for (int rr = 0; rr < 16; ++rr) {
            oaccA[0][rr] *= alpha; oaccA[1][rr] *= alpha;
            oaccB[0][rr] *= alpha; oaccB[1][rr] *= alpha;
          }
          mraw = mnew;
        }
        const float mC = mraw * C;
        float psum = 0.f;
#pragma unroll
        for (int t = 0; t < 2; ++t)
#pragma unroll
          for (int rr = 0; rr < 16; ++rr) {
            float pp = __builtin_exp2f(__builtin_fmaf(sa[t][rr], C, -mC));
            sa[t][rr] = pp;
            psum += pp;
          }
        lsum += halfcomb_sum(psum);

        // ---- P^T -> bf16 B-frags + PV (A/B split) ----
        __builtin_amdgcn_s_setprio(1);
#pragma unroll
        for (int t = 0; t < 2; ++t) {
#pragma unroll
          for (int half = 0; half < 2; ++half) {
            const int rb = half * 8;
            unsigned a0 = pack2bf(sa[t][rb + 0], sa[t][rb + 1]);
            unsigned a1 = pack2bf(sa[t][rb + 2], sa[t][rb + 3]);
            unsigned b0w = pack2bf(sa[t][rb + 4], sa[t][rb + 5]);
            unsigned b1w = pack2bf(sa[t][rb + 6], sa[t][rb + 7]);
            union { unsigned u[4]; bf16x8 v; } pf;
#ifdef HAVE_PL32
            pl32sw(a0, b0w);
            pl32sw(a1, b1w);
            pf.u[0] = a0; pf.u[1] = a1; pf.u[2] = b0w; pf.u[3] = b1w;
#else
            unsigned xa0 = __shfl_xor(a0, 32, 64);
            unsigned xa1 = __shfl_xor(a1, 32, 64);
            unsigned xb0 = __shfl_xor(b0w, 32, 64);
            unsigned xb1 = __shfl_xor(b1w, 32, 64);
            pf.u[0] = lo_half ? a0 : xb0;
            pf.u[1] = lo_half ? a1 : xb1;
            pf.u[2] = lo_half ? xa0 : b0w;
            pf.u[3] = lo_half ? xa1 : b1w;
#endif
            if (t == 0) {
              oaccA[0] = __builtin_amdgcn_mfma_f32_32x32x16_bf16(
                  vf[0][half], pf.v, oaccA[0], 0, 0, 0);
              oaccA[1] = __builtin_amdgcn_mfma_f32_32x32x16_bf16(
                  vf[1][half], pf.v, oaccA[1], 0, 0, 0);
            } else {
              oaccB[0] = __builtin_amdgcn_mfma_f32_32x32x16_bf16(
                  vf[0][2 + half], pf.v, oaccB[0], 0, 0, 0);
              oaccB[1] = __builtin_amdgcn_mfma_f32_32x32x16_bf16(
                  vf[1][2 + half], pf.v, oaccB[1], 0, 0, 0);
            }
          }
        }
        __builtin_amdgcn_s_setprio(0);
      }

      __syncthreads();  // stage complete + LDS reads done before overwrite
      buf ^= 1;
    }

    // combine the PV split before publish/merge
#pragma unroll
    for (int tt = 0; tt < 2; ++tt)
#pragma unroll
      for (int rr = 0; rr < 16; ++rr) oaccA[tt][rr] += oaccB[tt][rr];

    // ---- merge parity partials: p1 publishes, p0 merges + stores ----
    const int base = (wq * 64 + lane) * 37;  // 256 slots x 37 f32 = 38 KB
    if (p == 1) {
      scr[base + 0] = mraw;
      scr[base + 1] = lsum;
#pragma unroll
      for (int t = 0; t < 2; ++t)
#pragma unroll
        for (int rr = 0; rr < 16; ++rr)
          scr[base + 2 + t * 16 + rr] = oaccA[t][rr];
    }
    __syncthreads();
    if (p == 0) {
      const float mB = scr[base + 0], lB = scr[base + 1];
      const float mS = fmaxf(mraw, mB);
      const float aA = __builtin_exp2f((mraw - mS) * C);
      const float aB = __builtin_exp2f((mB - mS) * C);
      const float lT = lsum * aA + lB * aB;
      const float linv = 1.0f / lT;
      ushort* crow = &ctx[((size_t)(b * S_LEN) + qrow) * DMODEL + h * HDIM];
#pragma unroll
      for (int t = 0; t < 2; ++t)
#pragma unroll
        for (int g2 = 0; g2 < 4; ++g2) {
          ushort4 o;  // hd = t*32 + g2*8 + hi*4 + r
          float m0 = oaccA[t][g2 * 4 + 0] * aA + scr[base + 2 + t * 16 + g2 * 4 + 0] * aB;
          float m1 = oaccA[t][g2 * 4 + 1] * aA + scr[base + 2 + t * 16 + g2 * 4 + 1] * aB;
          float m2 = oaccA[t][g2 * 4 + 2] * aA + scr[base + 2 + t * 16 + g2 * 4 + 2] * aB;
          float m3 = oaccA[t][g2 * 4 + 3] * aA + scr[base + 2 + t * 16 + g2 * 4 + 3] * aB;
          o.x = f2bf(m0 * linv); o.y = f2bf(m1 * linv);
          o.z = f2bf(m2 * linv); o.w = f2bf(m3 * linv);
          *(ushort4*)&crow[t * 32 + g2 * 8 + hi * 4] = o;
        }
    }
    __syncthreads();  // scratch reads done before next phase restages LDS
  }
}

// ---------------- launch ----------------

extern "C" void kernel_launch(void* const* d_in, const int* in_sizes, int n_in,
                              void* d_out, int out_size, void* d_ws,
                              size_t ws_size, hipStream_t stream) {
  const float* x  = (const float*)d_in[0];
  const float* Wq = (const float*)d_in[1];
  const float* bq = (const float*)d_in[2];
  const float* Wk = (const float*)d_in[3];
  const float* bk = (const float*)d_in[4];
  const float* Wv = (const float*)d_in[5];
  const float* bv = (const float*)d_in[6];
  const float* Wo = (const float*)d_in[7];
  const float* bo = (const float*)d_in[8];

  char* ws = (char*)d_ws;
  ushort* Xbf = (ushort*)ws;                               // 8 MB
  ushort* WT  = (ushort*)(ws + (size_t)8 * 1024 * 1024);   // 8 MB
  ushort* QKV = (ushort*)(ws + (size_t)16 * 1024 * 1024);  // Q,K then Vt
  ushort* CTX = (ushort*)(ws + (size_t)40 * 1024 * 1024);  // V-rowmajor, ctx

  const size_t QKV_ELEMS = (size_t)MROWS * DMODEL;  // 4 M elems = 8 MB
  const size_t W_ELEMS = (size_t)DMODEL * DMODEL;

  ushort* Qp  = QKV;                  // [B,H,S,HD]
  ushort* Kp  = QKV + QKV_ELEMS;      // [B,H,S,HD]
  ushort* Vtp = QKV + 2 * QKV_ELEMS;  // [B,H,HD,S]  (trV output)
  ushort* Vrp = CTX;                  // [B,H,S,HD]  (gemm256 scratch out)

  cvt_x<<<4096, 256, 0, stream>>>(x, Xbf);
  cvt_wt<<<dim3(16, 16, 4), 256, 0, stream>>>(Wq, Wk, Wv, Wo, WT);
  gemm256<<<dim3(16, 16), 512, 0, stream>>>(Xbf, WT, bq, bk, bv, Qp, Kp, Vrp);
  trV<<<dim3(64, 2, 32), 256, 0, stream>>>(Vrp, Vtp);
  attn8<<<dim3(256), 512, 0, stream>>>(Qp, Kp, Vtp, CTX);
  gemm128o<<<dim3(32, 8), 256, 0, stream>>>(CTX, WT + 3 * W_ELEMS, bo,
                                            (float*)d_out);
}